// Round 5
// baseline (374.190 us; speedup 1.0000x reference)
//
#include <hip/hip_runtime.h>
#include <math.h>

#define B_ 4
#define C_ 256
#define CH_ 128
#define NN 4096   // H*W = 64*64
#define NP 4224   // padded V row stride: 8448 B = 33 x 256 B -> no L2 channel alias

typedef __bf16 bf16x8 __attribute__((ext_vector_type(8)));
typedef float f32x16 __attribute__((ext_vector_type(16)));
typedef unsigned int u32;

__device__ __forceinline__ float gelu_erf(float x) {
    return 0.5f * x * (1.0f + erff(x * 0.7071067811865476f));
}

// ---------------------------------------------------------------------------
// NCHW fp32 -> NHWC bf16 cast/transpose.
// ---------------------------------------------------------------------------
__global__ __launch_bounds__(256) void nhwc_cast_kernel(
    const float* __restrict__ src, __bf16* __restrict__ dst,
    int colbase, int rowstride)
{
    __shared__ float Lt[64][65];
    const int t = threadIdx.x;
    const int p0 = blockIdx.x * 64;
    const int c0 = blockIdx.y * 64;
    const int b  = blockIdx.z;
#pragma unroll
    for (int i = 0; i < 16; ++i) {
        int idx = t + i * 256;
        int c = idx >> 6, p = idx & 63;
        Lt[c][p] = src[((size_t)(b * 256 + c0 + c)) * 4096 + p0 + p];
    }
    __syncthreads();
#pragma unroll
    for (int i = 0; i < 16; ++i) {
        int idx = t + i * 256;
        int p = idx >> 6, c = idx & 63;
        dst[((size_t)(b * 4096 + p0 + p)) * rowstride + colbase + c0 + c] = (__bf16)Lt[c][p];
    }
}

// ---------------------------------------------------------------------------
// Weight transform: conv3x3 weights -> [k9][O][I] bf16; 1x1 weights -> bf16 copy
// ---------------------------------------------------------------------------
__global__ __launch_bounds__(256) void wtrans_kernel(
    const float* __restrict__ w0, const float* __restrict__ w1,
    const float* __restrict__ wq, const float* __restrict__ wk,
    const float* __restrict__ wv, const float* __restrict__ wo,
    __bf16* __restrict__ Wt0, __bf16* __restrict__ Wt1,
    __bf16* __restrict__ wqb, __bf16* __restrict__ wkb,
    __bf16* __restrict__ wvb, __bf16* __restrict__ wob)
{
    int id = blockIdx.x * 256 + threadIdx.x;
    if (id < 131072) {
        int o = id >> 9, ci = id & 511;
        const float* s = w0 + (size_t)id * 9;
#pragma unroll
        for (int k = 0; k < 9; ++k)
            Wt0[((size_t)k * 256 + o) * 512 + ci] = (__bf16)s[k];
    } else if (id < 196608) {
        int id2 = id - 131072;
        int o = id2 >> 8, ci = id2 & 255;
        const float* s = w1 + (size_t)id2 * 9;
#pragma unroll
        for (int k = 0; k < 9; ++k)
            Wt1[((size_t)k * 256 + o) * 256 + ci] = (__bf16)s[k];
    } else {
        int id3 = id - 196608;     // 0..131071
        int sel = id3 >> 15;
        int k = id3 & 32767;
        const float* s = sel == 0 ? wq : sel == 1 ? wk : sel == 2 ? wv : wo;
        __bf16* d = sel == 0 ? wqb : sel == 1 ? wkb : sel == 2 ? wvb : wob;
        d[k] = (__bf16)s[k];
    }
}

// ---------------------------------------------------------------------------
// 1x1 projections via MFMA. C[o][p] = sum_c W[o][c] X[p][c] + bias.
// which: 0 -> V (w_q on in0, ch-major out, padded stride NP, via LDS transpose)
//        1 -> K (w_k on in0, pos-major out)
//        2 -> Q (w_v on in1, pos-major out)
// ---------------------------------------------------------------------------
__global__ __launch_bounds__(256) void proj_mfma_kernel(
    const __bf16* __restrict__ Xt0,   // [4][4096][512], in0 at cols 256-511
    const __bf16* __restrict__ Xin1,  // [4][4096][256]
    const __bf16* __restrict__ wqb, const __bf16* __restrict__ wkb,
    const __bf16* __restrict__ wvb,
    const float* __restrict__ bq, const float* __restrict__ bk,
    const float* __restrict__ bv,
    __bf16* __restrict__ Vcm, __bf16* __restrict__ Kpm, __bf16* __restrict__ Qpm)
{
    __shared__ __align__(16) __bf16 Vt[4][64][80];
    __shared__ float biasl[128];

    const int t = threadIdx.x;
    const int which = blockIdx.z % 3;
    const int b = blockIdx.z / 3;
    const int p0 = blockIdx.x * 128;

    const __bf16* W = which == 0 ? wqb : which == 1 ? wkb : wvb;
    const float* bias = which == 0 ? bq : which == 1 ? bk : bv;
    const __bf16* src; int stride, colb;
    if (which == 2) { src = Xin1 + (size_t)b * NN * 256; stride = 256; colb = 0; }
    else            { src = Xt0  + (size_t)b * NN * 512; stride = 512; colb = 256; }

    if (t < 128) biasl[t] = bias[t];
    __syncthreads();

    const int lane = t & 63, w = t >> 6;
    const int l31 = lane & 31, hi = lane >> 5;
    const int wo2 = w >> 1, wp2 = w & 1;
    const int ob = wo2 * 64;
    const int pb = p0 + wp2 * 64;

    f32x16 acc[2][2];
#pragma unroll
    for (int i = 0; i < 2; ++i)
#pragma unroll
        for (int j = 0; j < 2; ++j)
#pragma unroll
            for (int e = 0; e < 16; ++e) acc[i][j][e] = 0.f;

#pragma unroll
    for (int kc = 0; kc < 16; ++kc) {
        bf16x8 a0 = *(const bf16x8*)&W[(size_t)(ob + l31) * 256 + hi * 8 + kc * 16];
        bf16x8 a1 = *(const bf16x8*)&W[(size_t)(ob + 32 + l31) * 256 + hi * 8 + kc * 16];
        bf16x8 b0 = *(const bf16x8*)&src[(size_t)(pb + l31) * stride + colb + hi * 8 + kc * 16];
        bf16x8 b1 = *(const bf16x8*)&src[(size_t)(pb + 32 + l31) * stride + colb + hi * 8 + kc * 16];
        acc[0][0] = __builtin_amdgcn_mfma_f32_32x32x16_bf16(a0, b0, acc[0][0], 0, 0, 0);
        acc[0][1] = __builtin_amdgcn_mfma_f32_32x32x16_bf16(a0, b1, acc[0][1], 0, 0, 0);
        acc[1][0] = __builtin_amdgcn_mfma_f32_32x32x16_bf16(a1, b0, acc[1][0], 0, 0, 0);
        acc[1][1] = __builtin_amdgcn_mfma_f32_32x32x16_bf16(a1, b1, acc[1][1], 0, 0, 0);
    }

    if (which) {
        __bf16* dst = (which == 1 ? Kpm : Qpm) + (size_t)b * NN * CH_;
#pragma unroll
        for (int mi = 0; mi < 2; ++mi)
#pragma unroll
            for (int nx = 0; nx < 2; ++nx) {
                const int p = pb + nx * 32 + l31;
#pragma unroll
                for (int q4 = 0; q4 < 4; ++q4) {
                    const int og = ob + mi * 32 + q4 * 8 + hi * 4;
                    __bf16 pk[4];
#pragma unroll
                    for (int j = 0; j < 4; ++j)
                        pk[j] = (__bf16)(acc[mi][nx][q4 * 4 + j] + biasl[og + j]);
                    *(uint2*)&dst[(size_t)p * CH_ + og] = *(const uint2*)pk;
                }
            }
    } else {
        // V: transpose through LDS, write ch-major (padded stride NP) coalesced
#pragma unroll
        for (int mi = 0; mi < 2; ++mi)
#pragma unroll
            for (int nx = 0; nx < 2; ++nx) {
                const int ploc = nx * 32 + l31;
#pragma unroll
                for (int q4 = 0; q4 < 4; ++q4) {
                    const int oloc = mi * 32 + q4 * 8 + hi * 4;
#pragma unroll
                    for (int j = 0; j < 4; ++j)
                        Vt[w][oloc + j][ploc] =
                            (__bf16)(acc[mi][nx][q4 * 4 + j] + biasl[ob + oloc + j]);
                }
            }
        __syncthreads();
#pragma unroll
        for (int s = 0; s < 8; ++s) {
            const int lin = s * 64 + lane;
            const int row = lin >> 3, ch = lin & 7;
            *(uint4*)&Vcm[((size_t)(b * CH_ + ob + row)) * NP + pb + ch * 8] =
                *(const uint4*)&Vt[w][row][ch * 8];
        }
    }
}

// ---------------------------------------------------------------------------
// MFMA bf16 flash attention, KV-split 8 (4 in-block waves x 2 block-halves).
// V is read with padded stride NP (no 8KB channel alias). No setprio, no
// defer-max branch (both regressed in R4).
// grid 1024, block 256.
// ---------------------------------------------------------------------------
__global__ __launch_bounds__(256, 2) void attn_mfma_kernel(
    const __bf16* __restrict__ Qpm, const __bf16* __restrict__ Kpm,
    const __bf16* __restrict__ Vcm,
    __bf16* __restrict__ Opart, float* __restrict__ Mpart, float* __restrict__ Lpart)
{
    __shared__ __bf16 Op[4][128][34];   // 34816 B
    __shared__ float Ml[4][32], Ll[4][32];

    const int t = threadIdx.x;
    const int lane = t & 63;
    const int w = t >> 6;
    const int l31 = lane & 31;
    const int hi = lane >> 5;

    const int bid = blockIdx.x;
    const int xcd = bid & 7;
    const int b = xcd >> 1;                      // 2 XCDs per batch
    const int local = bid >> 3;                  // 0..127
    const int qt = (xcd & 1) * 64 + (local & 63);
    const int half = local >> 6;
    const int q0 = qt * 32;

    // Q B-fragments in registers (8 i-chunks of 16)
    const __bf16* Qb = Qpm + ((size_t)(b * NN + q0 + l31)) * CH_ + hi * 8;
    bf16x8 qf[8];
#pragma unroll
    for (int ic = 0; ic < 8; ++ic) qf[ic] = *(const bf16x8*)(Qb + ic * 16);

    const __bf16* Kb = Kpm + (size_t)b * NN * CH_;
    const __bf16* Vb = Vcm + (size_t)b * CH_ * NP;

    f32x16 oacc[4];
#pragma unroll
    for (int i = 0; i < 4; ++i)
#pragma unroll
        for (int e = 0; e < 16; ++e) oacc[i][e] = 0.f;

    float m = -3e38f, lsum = 0.f;

    for (int jt = 0; jt < 8; ++jt) {
        const int j0 = (half * 32 + w * 8 + jt) * 64;
        f32x16 s0, s1;
#pragma unroll
        for (int e = 0; e < 16; ++e) { s0[e] = 0.f; s1[e] = 0.f; }
        const __bf16* Kt = Kb + (size_t)(j0 + l31) * CH_ + hi * 8;
#pragma unroll
        for (int ic = 0; ic < 8; ++ic) {
            bf16x8 kf0 = *(const bf16x8*)(Kt + ic * 16);
            bf16x8 kf1 = *(const bf16x8*)(Kt + 32 * CH_ + ic * 16);
            s0 = __builtin_amdgcn_mfma_f32_32x32x16_bf16(kf0, qf[ic], s0, 0, 0, 0);
            s1 = __builtin_amdgcn_mfma_f32_32x32x16_bf16(kf1, qf[ic], s1, 0, 0, 0);
        }
        // ---- online softmax over j (tree reductions, unconditional rescale) ----
        float tm[16];
#pragma unroll
        for (int e = 0; e < 16; ++e) tm[e] = fmaxf(s0[e], s1[e]);
#pragma unroll
        for (int off = 8; off > 0; off >>= 1)
#pragma unroll
            for (int e = 0; e < off; ++e) tm[e] = fmaxf(tm[e], tm[e + off]);
        const float pm = fmaxf(tm[0], __shfl_xor(tm[0], 32));
        const float mn = fmaxf(m, pm);
        const float al = __expf(m - mn);
        m = mn;
        float ts[16];
#pragma unroll
        for (int e = 0; e < 16; ++e) {
            s0[e] = __expf(s0[e] - mn);
            s1[e] = __expf(s1[e] - mn);
            ts[e] = s0[e] + s1[e];
        }
#pragma unroll
        for (int off = 8; off > 0; off >>= 1)
#pragma unroll
            for (int e = 0; e < off; ++e) ts[e] += ts[e + off];
        lsum = lsum * al + ts[0] + __shfl_xor(ts[0], 32);
#pragma unroll
        for (int i = 0; i < 4; ++i)
#pragma unroll
            for (int e = 0; e < 16; ++e) oacc[i][e] *= al;

        // ---- P (f32, C-layout) -> bf16 B-fragments (4 j-chunks of 16) ----
        u32 pf[4][4];
        {
            u32 wv[8], pw[8];
#pragma unroll
            for (int r = 0; r < 8; ++r) {
                union { __bf16 h[2]; u32 u; } x;
                x.h[0] = (__bf16)s0[2 * r]; x.h[1] = (__bf16)s0[2 * r + 1];
                wv[r] = x.u;
            }
#pragma unroll
            for (int r = 0; r < 8; ++r) pw[r] = (u32)__shfl_xor((int)wv[r], 32);
            pf[0][0] = hi ? pw[2] : wv[0];
            pf[0][1] = hi ? pw[3] : wv[1];
            pf[0][2] = hi ? wv[2] : pw[0];
            pf[0][3] = hi ? wv[3] : pw[1];
            pf[1][0] = hi ? pw[6] : wv[4];
            pf[1][1] = hi ? pw[7] : wv[5];
            pf[1][2] = hi ? wv[6] : pw[4];
            pf[1][3] = hi ? wv[7] : pw[5];
#pragma unroll
            for (int r = 0; r < 8; ++r) {
                union { __bf16 h[2]; u32 u; } x;
                x.h[0] = (__bf16)s1[2 * r]; x.h[1] = (__bf16)s1[2 * r + 1];
                wv[r] = x.u;
            }
#pragma unroll
            for (int r = 0; r < 8; ++r) pw[r] = (u32)__shfl_xor((int)wv[r], 32);
            pf[2][0] = hi ? pw[2] : wv[0];
            pf[2][1] = hi ? pw[3] : wv[1];
            pf[2][2] = hi ? wv[2] : pw[0];
            pf[2][3] = hi ? wv[3] : pw[1];
            pf[3][0] = hi ? pw[6] : wv[4];
            pf[3][1] = hi ? pw[7] : wv[5];
            pf[3][2] = hi ? wv[6] : pw[4];
            pf[3][3] = hi ? wv[7] : pw[5];
        }
        // ---- PV: O[i][k] += V[i][j] P[j][k] ----
        const __bf16* Vt = Vb + (size_t)l31 * NP + j0 + hi * 8;
#pragma unroll
        for (int icf = 0; icf < 4; ++icf) {
#pragma unroll
            for (int jc = 0; jc < 4; ++jc) {
                bf16x8 vf = *(const bf16x8*)(Vt + (size_t)(icf * 32) * NP + jc * 16);
                union { u32 u[4]; bf16x8 v; } cv;
#pragma unroll
                for (int q = 0; q < 4; ++q) cv.u[q] = pf[jc][q];
                oacc[icf] = __builtin_amdgcn_mfma_f32_32x32x16_bf16(vf, cv.v, oacc[icf], 0, 0, 0);
            }
        }
    }

    // ---- in-block merge across the 4 split-waves (bf16 partials) ----
#pragma unroll
    for (int icf = 0; icf < 4; ++icf)
#pragma unroll
        for (int q = 0; q < 16; ++q) {
            const int row = icf * 32 + (q & 3) + 8 * (q >> 2) + 4 * hi;
            Op[w][row][l31] = (__bf16)oacc[icf][q];
        }
    if (hi == 0) { Ml[w][l31] = m; Ll[w][l31] = lsum; }
    __syncthreads();
    {
        const int q = t & 31;
        const int i0g = (t >> 5) * 16;
        const float m0 = Ml[0][q], m1 = Ml[1][q], m2 = Ml[2][q], m3 = Ml[3][q];
        const float ms = fmaxf(fmaxf(m0, m1), fmaxf(m2, m3));
        const float a0 = __expf(m0 - ms), a1 = __expf(m1 - ms);
        const float a2 = __expf(m2 - ms), a3 = __expf(m3 - ms);
        const float den = a0 * Ll[0][q] + a1 * Ll[1][q] + a2 * Ll[2][q] + a3 * Ll[3][q];
        union { __bf16 h[16]; uint4 u4[2]; } pk;
#pragma unroll
        for (int ii = 0; ii < 16; ++ii) {
            const int i = i0g + ii;
            pk.h[ii] = (__bf16)(a0 * (float)Op[0][i][q] + a1 * (float)Op[1][i][q]
                              + a2 * (float)Op[2][i][q] + a3 * (float)Op[3][i][q]);
        }
        const size_t base = ((size_t)((half * 4 + b) * NN) + q0 + q) * CH_ + i0g;
        *(uint4*)&Opart[base] = pk.u4[0];
        *(uint4*)&Opart[base + 8] = pk.u4[1];
        if (t < 32) {
            Mpart[(size_t)(half * 4 + b) * NN + q0 + q] = ms;
            Lpart[(size_t)(half * 4 + b) * NN + q0 + q] = den;
        }
    }
}

// ---------------------------------------------------------------------------
// Merge the 2 KV-half partials -> x0 bf16 pos-major [4][4096][128]
// ---------------------------------------------------------------------------
__global__ __launch_bounds__(256) void attn_merge_kernel(
    const __bf16* __restrict__ Opart, const float* __restrict__ Mpart,
    const float* __restrict__ Lpart, __bf16* __restrict__ x0)
{
    const int id = blockIdx.x * 256 + threadIdx.x;   // 65536
    const int qg = id >> 2;
    const int i0 = (id & 3) * 32;
    const int b = qg >> 12, q = qg & 4095;
    const size_t idx0 = (size_t)b * NN + q;
    const size_t idx1 = (size_t)(4 + b) * NN + q;
    const float m0 = Mpart[idx0], m1 = Mpart[idx1];
    const float ms = fmaxf(m0, m1);
    const float a0 = __expf(m0 - ms), a1 = __expf(m1 - ms);
    const float inv = 1.f / (a0 * Lpart[idx0] + a1 * Lpart[idx1]);
    const __bf16* O0 = &Opart[idx0 * CH_ + i0];
    const __bf16* O1 = &Opart[idx1 * CH_ + i0];
    union { __bf16 h[32]; uint4 u4[4]; } ov;
#pragma unroll
    for (int ii = 0; ii < 32; ++ii)
        ov.h[ii] = (__bf16)((a0 * (float)O0[ii] + a1 * (float)O1[ii]) * inv);
    uint4* dst = (uint4*)&x0[((size_t)b * NN + q) * CH_ + i0];
#pragma unroll
    for (int s = 0; s < 4; ++s) dst[s] = ov.u4[s];
}

// ---------------------------------------------------------------------------
// conv_o (1x1, 128->256) via MFMA + BN + GELU -> Xt0 cols 0-255 (NHWC bf16)
// ---------------------------------------------------------------------------
__global__ __launch_bounds__(256) void convo_mfma_kernel(
    const __bf16* __restrict__ x0, const __bf16* __restrict__ wob,
    const float* __restrict__ bo,
    const float* __restrict__ g, const float* __restrict__ bb,
    const float* __restrict__ mm, const float* __restrict__ vv,
    __bf16* __restrict__ Xt0)
{
    __shared__ float scb[128], shb[128], bsb[128];
    const int t = threadIdx.x;
    const int p0 = blockIdx.x * 128;
    const int o0 = blockIdx.y * 128;
    const int b = blockIdx.z;
    if (t < 128) {
        const int o = o0 + t;
        const float sc = g[o] * rsqrtf(vv[o] + 1e-5f);
        scb[t] = sc; shb[t] = bb[o] - mm[o] * sc; bsb[t] = bo[o];
    }
    __syncthreads();

    const int lane = t & 63, w = t >> 6;
    const int l31 = lane & 31, hi = lane >> 5;
    const int wo2 = w >> 1, wp2 = w & 1;
    const int ob = o0 + wo2 * 64;
    const int pb = p0 + wp2 * 64;

    f32x16 acc[2][2];
#pragma unroll
    for (int i = 0; i < 2; ++i)
#pragma unroll
        for (int j = 0; j < 2; ++j)
#pragma unroll
            for (int e = 0; e < 16; ++e) acc[i][j][e] = 0.f;

#pragma unroll
    for (int kc = 0; kc < 8; ++kc) {
        bf16x8 a0 = *(const bf16x8*)&wob[(size_t)(ob + l31) * 128 + hi * 8 + kc * 16];
        bf16x8 a1 = *(const bf16x8*)&wob[(size_t)(ob + 32 + l31) * 128 + hi * 8 + kc * 16];
        bf16x8 b0 = *(const bf16x8*)&x0[((size_t)(b * NN) + pb + l31) * 128 + hi * 8 + kc * 16];
        bf16x8 b1 = *(const bf16x8*)&x0[((size_t)(b * NN) + pb + 32 + l31) * 128 + hi * 8 + kc * 16];
        acc[0][0] = __builtin_amdgcn_mfma_f32_32x32x16_bf16(a0, b0, acc[0][0], 0, 0, 0);
        acc[0][1] = __builtin_amdgcn_mfma_f32_32x32x16_bf16(a0, b1, acc[0][1], 0, 0, 0);
        acc[1][0] = __builtin_amdgcn_mfma_f32_32x32x16_bf16(a1, b0, acc[1][0], 0, 0, 0);
        acc[1][1] = __builtin_amdgcn_mfma_f32_32x32x16_bf16(a1, b1, acc[1][1], 0, 0, 0);
    }

#pragma unroll
    for (int mi = 0; mi < 2; ++mi)
#pragma unroll
        for (int nx = 0; nx < 2; ++nx) {
            const int p = pb + nx * 32 + l31;
            const size_t rowbase = ((size_t)(b * NN) + p) * 512 + o0;
#pragma unroll
            for (int q4 = 0; q4 < 4; ++q4) {
                const int ol = wo2 * 64 + mi * 32 + q4 * 8 + hi * 4;
                __bf16 pk[4];
#pragma unroll
                for (int j = 0; j < 4; ++j) {
                    float v = acc[mi][nx][q4 * 4 + j] + bsb[ol + j];
                    v = v * scb[ol + j] + shb[ol + j];
                    pk[j] = (__bf16)gelu_erf(v);
                }
                *(uint2*)&Xt0[rowbase + ol] = *(const uint2*)pk;
            }
        }
}

// ---------------------------------------------------------------------------
// 3x3 conv via MFMA (implicit GEMM), NHWC bf16 in/out, BN+GELU. (unchanged)
// ---------------------------------------------------------------------------
template<int IC>
__global__ __launch_bounds__(256) void conv3x3_mfma_kernel(
    const __bf16* __restrict__ Xsrc,   // NHWC [4][4096][IC]
    const __bf16* __restrict__ Wt,     // [9][256][IC]
    const float* __restrict__ bias, const float* __restrict__ bng,
    const float* __restrict__ bnb, const float* __restrict__ bnm,
    const float* __restrict__ bnv,
    __bf16* __restrict__ out)          // NHWC [4][4096][256]
{
    constexpr int NC = IC / 16;
    __shared__ __align__(16) char Wl[2][18432];
    __shared__ __align__(16) char Tl[2][13824];
    __shared__ float scb[64], shb[64], bsb[64];

    const int t = threadIdx.x;
    const int bid = blockIdx.x;
    const int xcd = bid & 7, local = bid >> 3;
    const int combo = xcd * 2 + (local >> 4);
    const int pt = local & 15;
    const int m = combo & 3, b = combo >> 2;
    const int o0 = m * 64;
    const int y0 = pt * 4;

    if (t < 64) {
        const int o = o0 + t;
        const float sc = bng[o] * rsqrtf(bnv[o] + 1e-5f);
        scb[t] = sc; shb[t] = bnb[o] - bnm[o] * sc; bsb[t] = bias[o];
    }

    const int lane = t & 63, w = t >> 6;
    const int l31 = lane & 31, hi = lane >> 5;

    uint4 wreg[5], ireg[3];

    auto loadW = [&](int c0) {
#pragma unroll
        for (int s = 0; s < 5; ++s) {
            int u = t + s * 256;
            if (u < 1152) {
                int g = u & 1, o = (u >> 1) & 63, k9 = u >> 7;
                wreg[s] = *(const uint4*)&Wt[((size_t)(k9 * 256 + o0 + o)) * IC + c0 + g * 8];
            }
        }
    };
    auto loadI = [&](int c0) {
#pragma unroll
        for (int s = 0; s < 3; ++s) {
            int u = t + s * 256;
            int g = u & 1, x = (u >> 1) & 63, r = u >> 7;
            int yy = y0 - 1 + r;
            if (yy >= 0 && yy < 64)
                ireg[s] = *(const uint4*)&Xsrc[((size_t)(b * 4096 + yy * 64 + x)) * IC + c0 + g * 8];
            else
                ireg[s] = make_uint4(0u, 0u, 0u, 0u);
        }
    };
    auto writeW = [&](char* dst) {
#pragma unroll
        for (int s = 0; s < 5; ++s) {
            int u = t + s * 256;
            if (u < 1152) {
                int g = u & 1, o = (u >> 1) & 63, k9 = u >> 7;
                int byte = ((k9 * 64 + o) * 32 + g * 16) ^ ((o & 7) << 4);
                *(uint4*)(dst + byte) = wreg[s];
            }
        }
    };
    auto writeI = [&](char* dst) {
#pragma unroll
        for (int s = 0; s < 3; ++s) {
            int u = t + s * 256;
            int g = u & 1, x = (u >> 1) & 63, r = u >> 7;
            int xh = x + 1;
            int byte = (r * 2304 + xh * 32 + g * 16) ^ ((xh & 7) << 4);
            *(uint4*)(dst + byte) = ireg[s];
        }
        if (t < 24) {
            int g = t & 1, side = (t >> 1) & 1, r = t >> 2;
            int xh = side ? 65 : 0;
            int byte = (r * 2304 + xh * 32 + g * 16) ^ ((xh & 7) << 4);
            *(uint4*)(dst + byte) = make_uint4(0u, 0u, 0u, 0u);
        }
    };

    f32x16 acc[2][2];
#pragma unroll
    for (int i = 0; i < 2; ++i)
#pragma unroll
        for (int j = 0; j < 2; ++j)
#pragma unroll
            for (int e = 0; e < 16; ++e) acc[i][j][e] = 0.f;

    const int Abase = (l31 * 32 + hi * 16) ^ ((l31 & 7) << 4);
    int Bbase[3];
#pragma unroll
    for (int dx = 0; dx < 3; ++dx) {
        int xh = dx + l31;
        Bbase[dx] = (xh * 32 + hi * 16) ^ ((xh & 7) << 4);
    }

    auto compute = [&](const char* Wb, const char* Tb) {
#pragma unroll
        for (int k9 = 0; k9 < 9; ++k9) {
            const int dy = k9 / 3, dx = k9 % 3;
            bf16x8 a0 = *(const bf16x8*)(Wb + k9 * 2048 + Abase);
            bf16x8 a1 = *(const bf16x8*)(Wb + k9 * 2048 + 1024 + Abase);
            const char* Trow = Tb + (w + dy) * 2304;
#pragma unroll
            for (int nx = 0; nx < 2; ++nx) {
                bf16x8 bv = *(const bf16x8*)(Trow + nx * 1024 + Bbase[dx]);
                acc[0][nx] = __builtin_amdgcn_mfma_f32_32x32x16_bf16(a0, bv, acc[0][nx], 0, 0, 0);
                acc[1][nx] = __builtin_amdgcn_mfma_f32_32x32x16_bf16(a1, bv, acc[1][nx], 0, 0, 0);
            }
        }
    };

    loadW(0); loadI(0);
    writeW(Wl[0]); writeI(Tl[0]);
    __syncthreads();
    for (int c = 0; c < NC; ++c) {
        const int cur = c & 1;
        if (c + 1 < NC) { loadW((c + 1) * 16); loadI((c + 1) * 16); }
        compute(Wl[cur], Tl[cur]);
        __syncthreads();
        if (c + 1 < NC) { writeW(Wl[cur ^ 1]); writeI(Tl[cur ^ 1]); }
        __syncthreads();
    }

#pragma unroll
    for (int mi = 0; mi < 2; ++mi)
#pragma unroll
        for (int nx = 0; nx < 2; ++nx) {
            const int x = nx * 32 + l31;
            const int p = (y0 + w) * 64 + x;
            const size_t rowbase = ((size_t)(b * 4096 + p)) * 256 + o0;
#pragma unroll
            for (int q = 0; q < 4; ++q) {
                const int obase = mi * 32 + q * 8 + hi * 4;
                __bf16 pk[4];
#pragma unroll
                for (int j = 0; j < 4; ++j) {
                    float v = acc[mi][nx][q * 4 + j] + bsb[obase + j];
                    v = v * scb[obase + j] + shb[obase + j];
                    pk[j] = (__bf16)gelu_erf(v);
                }
                *(uint2*)&out[rowbase + obase] = *(const uint2*)pk;
            }
        }
}

// ---------------------------------------------------------------------------
// global max of (y1 + x0gelu) over spatial, two stages
// ---------------------------------------------------------------------------
__global__ __launch_bounds__(256) void maxpart_kernel(
    const __bf16* __restrict__ y1, const __bf16* __restrict__ xt0,
    float* __restrict__ part)
{
    const int o = threadIdx.x;
    const int chunk = blockIdx.x & 63;
    const int b = blockIdx.x >> 6;
    float mx = -1e30f;
    for (int pp = 0; pp < 64; ++pp) {
        int p = chunk * 64 + pp;
        float a = (float)y1[((size_t)(b * 4096 + p)) * 256 + o];
        float c = (float)xt0[((size_t)(b * 4096 + p)) * 512 + o];
        mx = fmaxf(mx, a + c);
    }
    part[((size_t)(b * 64 + chunk)) * 256 + o] = mx;
}

__global__ __launch_bounds__(256) void maxfin_kernel(
    const float* __restrict__ part, float* __restrict__ out)
{
    const int o = threadIdx.x;
    const int b = blockIdx.x;
    float mx = -1e30f;
    for (int c = 0; c < 64; ++c)
        mx = fmaxf(mx, part[((size_t)(b * 64 + c)) * 256 + o]);
    out[b * 256 + o] = mx;
}

// ---------------------------------------------------------------------------
extern "C" void kernel_launch(void* const* d_in, const int* in_sizes, int n_in,
                              void* d_out, int out_size, void* d_ws, size_t ws_size,
                              hipStream_t stream)
{
    const float* in0  = (const float*)d_in[0];
    const float* in1  = (const float*)d_in[1];
    const float* w_q  = (const float*)d_in[2];
    const float* b_q  = (const float*)d_in[3];
    const float* w_k  = (const float*)d_in[4];
    const float* b_k  = (const float*)d_in[5];
    const float* w_v  = (const float*)d_in[6];
    const float* b_v  = (const float*)d_in[7];
    const float* w_o  = (const float*)d_in[8];
    const float* b_o  = (const float*)d_in[9];
    const float* bn0g = (const float*)d_in[10];
    const float* bn0b = (const float*)d_in[11];
    const float* bn0m = (const float*)d_in[12];
    const float* bn0v = (const float*)d_in[13];
    const float* cbw0 = (const float*)d_in[14];
    const float* cbb0 = (const float*)d_in[15];
    const float* cb0g = (const float*)d_in[16];
    const float* cb0b = (const float*)d_in[17];
    const float* cb0m = (const float*)d_in[18];
    const float* cb0v = (const float*)d_in[19];
    const float* cbw1 = (const float*)d_in[20];
    const float* cbb1 = (const float*)d_in[21];
    const float* cb1g = (const float*)d_in[22];
    const float* cb1b = (const float*)d_in[23];
    const float* cb1m = (const float*)d_in[24];
    const float* cb1v = (const float*)d_in[25];

    char* wsb = (char*)d_ws;
    const size_t MB = 1u << 20;
    // 0-16MB:   Xt0 [4][4096][512] bf16 (cols 0-255 convo out, 256-511 in0)
    // 16-24MB:  Xin1 [4][4096][256] bf16; dead after proj -> Opart [2][4][4096][128]
    // 24-28MB:  Qpm; dead after attn -> x0 (attn_merge out); then y0 covers 24-32
    // 28-32MB:  Kpm; dead after attn
    // 32-36.4:  Vcm [4][128][4224] bf16; dead after attn -> y1 covers 32-40
    // 40MB+:    weights bf16, Mpart/Lpart, part
    __bf16* Xt0  = (__bf16*)(wsb);
    __bf16* Xin1 = (__bf16*)(wsb + 16 * MB);
    __bf16* Opart= (__bf16*)(wsb + 16 * MB);
    __bf16* Qpm  = (__bf16*)(wsb + 24 * MB);
    __bf16* x0   = (__bf16*)(wsb + 24 * MB);
    __bf16* Kpm  = (__bf16*)(wsb + 28 * MB);
    __bf16* y0   = (__bf16*)(wsb + 24 * MB);
    __bf16* Vcm  = (__bf16*)(wsb + 32 * MB);
    __bf16* y1   = (__bf16*)(wsb + 32 * MB);
    __bf16* wqb  = (__bf16*)(wsb + 40 * MB);
    __bf16* wkb  = (__bf16*)(wsb + 40 * MB + 65536);
    __bf16* wvb  = (__bf16*)(wsb + 40 * MB + 2 * 65536);
    __bf16* wob  = (__bf16*)(wsb + 40 * MB + 3 * 65536);
    __bf16* Wt0  = (__bf16*)(wsb + 40 * MB + 4 * 65536);              // 2359296 B
    __bf16* Wt1  = (__bf16*)(wsb + 40 * MB + 4 * 65536 + 2359296);    // 1179648 B
    float*  Mpart= (float*)(wsb + 44 * MB);                            // 128KB
    float*  Lpart= (float*)(wsb + 44 * MB + 131072);                   // 128KB
    float*  part = (float*)(wsb + 44 * MB + 2 * 131072);               // 256KB
    float* outp = (float*)d_out;

    nhwc_cast_kernel<<<dim3(64, 4, 4), 256, 0, stream>>>(in0, Xt0, 256, 512);
    nhwc_cast_kernel<<<dim3(64, 4, 4), 256, 0, stream>>>(in1, Xin1, 0, 256);
    wtrans_kernel<<<1280, 256, 0, stream>>>(cbw0, cbw1, w_q, w_k, w_v, w_o,
                                            Wt0, Wt1, wqb, wkb, wvb, wob);
    proj_mfma_kernel<<<dim3(32, 1, 12), 256, 0, stream>>>(
        Xt0, Xin1, wqb, wkb, wvb, b_q, b_k, b_v, Vcm, Kpm, Qpm);
    attn_mfma_kernel<<<1024, 256, 0, stream>>>(Qpm, Kpm, Vcm, Opart, Mpart, Lpart);
    attn_merge_kernel<<<256, 256, 0, stream>>>(Opart, Mpart, Lpart, x0);
    convo_mfma_kernel<<<dim3(32, 2, 4), 256, 0, stream>>>(
        x0, wob, b_o, bn0g, bn0b, bn0m, bn0v, Xt0);
    conv3x3_mfma_kernel<512><<<256, 256, 0, stream>>>(Xt0, Wt0, cbb0, cb0g, cb0b, cb0m, cb0v, y0);
    conv3x3_mfma_kernel<256><<<256, 256, 0, stream>>>(y0, Wt1, cbb1, cb1g, cb1b, cb1m, cb1v, y1);
    maxpart_kernel<<<256, 256, 0, stream>>>(y1, Xt0, part);
    maxfin_kernel<<<4, 256, 0, stream>>>(part, outp);
}

// Round 7
// 371.622 us; speedup vs baseline: 1.0069x; 1.0069x over previous
//
#include <hip/hip_runtime.h>
#include <math.h>

#define B_ 4
#define C_ 256
#define CH_ 128
#define NN 4096   // H*W = 64*64
#define NP 4224   // padded V row stride

typedef __bf16 bf16x8 __attribute__((ext_vector_type(8)));
typedef float f32x16 __attribute__((ext_vector_type(16)));
typedef unsigned int u32;

__device__ __forceinline__ float gelu_erf(float x) {
    return 0.5f * x * (1.0f + erff(x * 0.7071067811865476f));
}

__device__ __forceinline__ u32 pkbf(float a, float b) {
    union { __bf16 h[2]; u32 u; } x;
    x.h[0] = (__bf16)a; x.h[1] = (__bf16)b;
    return x.u;
}

// ---------------------------------------------------------------------------
// NCHW fp32 -> NHWC bf16 cast/transpose.
// ---------------------------------------------------------------------------
__global__ __launch_bounds__(256) void nhwc_cast_kernel(
    const float* __restrict__ src, __bf16* __restrict__ dst,
    int colbase, int rowstride)
{
    __shared__ float Lt[64][65];
    const int t = threadIdx.x;
    const int p0 = blockIdx.x * 64;
    const int c0 = blockIdx.y * 64;
    const int b  = blockIdx.z;
#pragma unroll
    for (int i = 0; i < 16; ++i) {
        int idx = t + i * 256;
        int c = idx >> 6, p = idx & 63;
        Lt[c][p] = src[((size_t)(b * 256 + c0 + c)) * 4096 + p0 + p];
    }
    __syncthreads();
#pragma unroll
    for (int i = 0; i < 16; ++i) {
        int idx = t + i * 256;
        int p = idx >> 6, c = idx & 63;
        dst[((size_t)(b * 4096 + p0 + p)) * rowstride + colbase + c0 + c] = (__bf16)Lt[c][p];
    }
}

// ---------------------------------------------------------------------------
// Weight transform: conv3x3 weights -> [k9][O][I] bf16; 1x1 weights -> bf16 copy
// ---------------------------------------------------------------------------
__global__ __launch_bounds__(256) void wtrans_kernel(
    const float* __restrict__ w0, const float* __restrict__ w1,
    const float* __restrict__ wq, const float* __restrict__ wk,
    const float* __restrict__ wv, const float* __restrict__ wo,
    __bf16* __restrict__ Wt0, __bf16* __restrict__ Wt1,
    __bf16* __restrict__ wqb, __bf16* __restrict__ wkb,
    __bf16* __restrict__ wvb, __bf16* __restrict__ wob)
{
    int id = blockIdx.x * 256 + threadIdx.x;
    if (id < 131072) {
        int o = id >> 9, ci = id & 511;
        const float* s = w0 + (size_t)id * 9;
#pragma unroll
        for (int k = 0; k < 9; ++k)
            Wt0[((size_t)k * 256 + o) * 512 + ci] = (__bf16)s[k];
    } else if (id < 196608) {
        int id2 = id - 131072;
        int o = id2 >> 8, ci = id2 & 255;
        const float* s = w1 + (size_t)id2 * 9;
#pragma unroll
        for (int k = 0; k < 9; ++k)
            Wt1[((size_t)k * 256 + o) * 256 + ci] = (__bf16)s[k];
    } else {
        int id3 = id - 196608;     // 0..131071
        int sel = id3 >> 15;
        int k = id3 & 32767;
        const float* s = sel == 0 ? wq : sel == 1 ? wk : sel == 2 ? wv : wo;
        __bf16* d = sel == 0 ? wqb : sel == 1 ? wkb : sel == 2 ? wvb : wob;
        d[k] = (__bf16)s[k];
    }
}

// ---------------------------------------------------------------------------
// 1x1 projections via MFMA. (unchanged)
// ---------------------------------------------------------------------------
__global__ __launch_bounds__(256) void proj_mfma_kernel(
    const __bf16* __restrict__ Xt0,   // [4][4096][512], in0 at cols 256-511
    const __bf16* __restrict__ Xin1,  // [4][4096][256]
    const __bf16* __restrict__ wqb, const __bf16* __restrict__ wkb,
    const __bf16* __restrict__ wvb,
    const float* __restrict__ bq, const float* __restrict__ bk,
    const float* __restrict__ bv,
    __bf16* __restrict__ Vcm, __bf16* __restrict__ Kpm, __bf16* __restrict__ Qpm)
{
    __shared__ __align__(16) __bf16 Vt[4][64][80];
    __shared__ float biasl[128];

    const int t = threadIdx.x;
    const int which = blockIdx.z % 3;
    const int b = blockIdx.z / 3;
    const int p0 = blockIdx.x * 128;

    const __bf16* W = which == 0 ? wqb : which == 1 ? wkb : wvb;
    const float* bias = which == 0 ? bq : which == 1 ? bk : bv;
    const __bf16* src; int stride, colb;
    if (which == 2) { src = Xin1 + (size_t)b * NN * 256; stride = 256; colb = 0; }
    else            { src = Xt0  + (size_t)b * NN * 512; stride = 512; colb = 256; }

    if (t < 128) biasl[t] = bias[t];
    __syncthreads();

    const int lane = t & 63, w = t >> 6;
    const int l31 = lane & 31, hi = lane >> 5;
    const int wo2 = w >> 1, wp2 = w & 1;
    const int ob = wo2 * 64;
    const int pb = p0 + wp2 * 64;

    f32x16 acc[2][2];
#pragma unroll
    for (int i = 0; i < 2; ++i)
#pragma unroll
        for (int j = 0; j < 2; ++j)
#pragma unroll
            for (int e = 0; e < 16; ++e) acc[i][j][e] = 0.f;

#pragma unroll
    for (int kc = 0; kc < 16; ++kc) {
        bf16x8 a0 = *(const bf16x8*)&W[(size_t)(ob + l31) * 256 + hi * 8 + kc * 16];
        bf16x8 a1 = *(const bf16x8*)&W[(size_t)(ob + 32 + l31) * 256 + hi * 8 + kc * 16];
        bf16x8 b0 = *(const bf16x8*)&src[(size_t)(pb + l31) * stride + colb + hi * 8 + kc * 16];
        bf16x8 b1 = *(const bf16x8*)&src[(size_t)(pb + 32 + l31) * stride + colb + hi * 8 + kc * 16];
        acc[0][0] = __builtin_amdgcn_mfma_f32_32x32x16_bf16(a0, b0, acc[0][0], 0, 0, 0);
        acc[0][1] = __builtin_amdgcn_mfma_f32_32x32x16_bf16(a0, b1, acc[0][1], 0, 0, 0);
        acc[1][0] = __builtin_amdgcn_mfma_f32_32x32x16_bf16(a1, b0, acc[1][0], 0, 0, 0);
        acc[1][1] = __builtin_amdgcn_mfma_f32_32x32x16_bf16(a1, b1, acc[1][1], 0, 0, 0);
    }

    if (which) {
        __bf16* dst = (which == 1 ? Kpm : Qpm) + (size_t)b * NN * CH_;
#pragma unroll
        for (int mi = 0; mi < 2; ++mi)
#pragma unroll
            for (int nx = 0; nx < 2; ++nx) {
                const int p = pb + nx * 32 + l31;
#pragma unroll
                for (int q4 = 0; q4 < 4; ++q4) {
                    const int og = ob + mi * 32 + q4 * 8 + hi * 4;
                    __bf16 pk[4];
#pragma unroll
                    for (int j = 0; j < 4; ++j)
                        pk[j] = (__bf16)(acc[mi][nx][q4 * 4 + j] + biasl[og + j]);
                    *(uint2*)&dst[(size_t)p * CH_ + og] = *(const uint2*)pk;
                }
            }
    } else {
        // V: transpose through LDS, write ch-major (padded stride NP) coalesced
#pragma unroll
        for (int mi = 0; mi < 2; ++mi)
#pragma unroll
            for (int nx = 0; nx < 2; ++nx) {
                const int ploc = nx * 32 + l31;
#pragma unroll
                for (int q4 = 0; q4 < 4; ++q4) {
                    const int oloc = mi * 32 + q4 * 8 + hi * 4;
#pragma unroll
                    for (int j = 0; j < 4; ++j)
                        Vt[w][oloc + j][ploc] =
                            (__bf16)(acc[mi][nx][q4 * 4 + j] + biasl[ob + oloc + j]);
                }
            }
        __syncthreads();
#pragma unroll
        for (int s = 0; s < 8; ++s) {
            const int lin = s * 64 + lane;
            const int row = lin >> 3, ch = lin & 7;
            *(uint4*)&Vcm[((size_t)(b * CH_ + ob + row)) * NP + pb + ch * 8] =
                *(const uint4*)&Vt[w][row][ch * 8];
        }
    }
}

// ---------------------------------------------------------------------------
// MFMA bf16 flash attention. 32-key iterations; permlane32_swap asm only for
// the P-pack (distinct-value operands -> no coalescing hazard); scalar
// max/sum exchange via __shfl_xor (R5-proven; R6's same-value "+v" asm pair
// was register-coalesced into v_permlane32_swap v5,v5 -> wrong max -> blowup).
// grid 1024, block 256 (4 waves x KV-split-8 with 2 block-halves).
// ---------------------------------------------------------------------------
__global__ __launch_bounds__(256, 4) void attn_mfma_kernel(
    const __bf16* __restrict__ Qpm, const __bf16* __restrict__ Kpm,
    const __bf16* __restrict__ Vcm,
    __bf16* __restrict__ Opart, float* __restrict__ Mpart, float* __restrict__ Lpart)
{
    __shared__ __bf16 Op[4][128][34];   // 34816 B
    __shared__ float Ml[4][32], Ll[4][32];

    const int t = threadIdx.x;
    const int lane = t & 63;
    const int w = t >> 6;
    const int l31 = lane & 31;
    const int hi = lane >> 5;

    const int bid = blockIdx.x;
    const int xcd = bid & 7;
    const int b = xcd >> 1;                      // 2 XCDs per batch
    const int local = bid >> 3;                  // 0..127
    const int qt = (xcd & 1) * 64 + (local & 63);
    const int half = local >> 6;
    const int q0 = qt * 32;

    // Q B-fragments in registers (8 i-chunks of 16)
    const __bf16* Qb = Qpm + ((size_t)(b * NN + q0 + l31)) * CH_ + hi * 8;
    bf16x8 qf[8];
#pragma unroll
    for (int ic = 0; ic < 8; ++ic) qf[ic] = *(const bf16x8*)(Qb + ic * 16);

    const __bf16* Kb = Kpm + (size_t)b * NN * CH_;
    const __bf16* Vb = Vcm + (size_t)b * CH_ * NP;

    f32x16 oacc[4];
#pragma unroll
    for (int i = 0; i < 4; ++i)
#pragma unroll
        for (int e = 0; e < 16; ++e) oacc[i][e] = 0.f;

    float m = -3e38f, lsum = 0.f;
    const int jbase = (half * 32 + w * 8) * 64;   // 512 keys per wave

    for (int jt = 0; jt < 16; ++jt) {
        const int j0 = jbase + jt * 32;
        // ---- QK^T: S[j=32 keys][k=32 queries], K rows as A, Q as B ----
        f32x16 s;
#pragma unroll
        for (int e = 0; e < 16; ++e) s[e] = 0.f;
        const __bf16* Kt = Kb + (size_t)(j0 + l31) * CH_ + hi * 8;
#pragma unroll
        for (int ic = 0; ic < 8; ++ic) {
            bf16x8 kf = *(const bf16x8*)(Kt + ic * 16);
            s = __builtin_amdgcn_mfma_f32_32x32x16_bf16(kf, qf[ic], s, 0, 0, 0);
        }
        // ---- tile max (in-lane tree + shfl cross-half) ----
        float t8[8];
#pragma unroll
        for (int e = 0; e < 8; ++e) t8[e] = fmaxf(s[e], s[e + 8]);
#pragma unroll
        for (int e = 0; e < 4; ++e) t8[e] = fmaxf(t8[e], t8[e + 4]);
        t8[0] = fmaxf(t8[0], t8[2]); t8[1] = fmaxf(t8[1], t8[3]);
        float mu = fmaxf(t8[0], t8[1]);
        const float pm = fmaxf(mu, __shfl_xor(mu, 32));
        // ---- defer-max rescale (skip O-rescale when max growth <= 8) ----
        if (!__all(pm <= m + 8.f)) {
            const float mn = fmaxf(m, pm);
            const float al = __expf(m - mn);
            m = mn;
            lsum *= al;
#pragma unroll
            for (int i = 0; i < 4; ++i)
#pragma unroll
                for (int e = 0; e < 16; ++e) oacc[i][e] *= al;
        }
        // ---- exp + tile sum ----
#pragma unroll
        for (int e = 0; e < 16; ++e) s[e] = __expf(s[e] - m);
        float s8[8];
#pragma unroll
        for (int e = 0; e < 8; ++e) s8[e] = s[e] + s[e + 8];
#pragma unroll
        for (int e = 0; e < 4; ++e) s8[e] += s8[e + 4];
        s8[0] += s8[2]; s8[1] += s8[3];
        float su = s8[0] + s8[1];
        lsum += su + __shfl_xor(su, 32);

        // ---- pack P->bf16 B-frags via permlane32_swap, PV per 16-key chunk ----
        const __bf16* Vt = Vb + (size_t)l31 * NP + j0 + hi * 8;
        {   // jc=0: keys j0..j0+15 from s[0..7]
            u32 w0 = pkbf(s[0], s[1]), w1 = pkbf(s[2], s[3]);
            u32 w2 = pkbf(s[4], s[5]), w3 = pkbf(s[6], s[7]);
            asm("v_permlane32_swap_b32 %0, %1" : "+v"(w0), "+v"(w2));
            asm("v_permlane32_swap_b32 %0, %1" : "+v"(w1), "+v"(w3));
            union { u32 u4[4]; bf16x8 v; } pB;
            pB.u4[0] = w0; pB.u4[1] = w1; pB.u4[2] = w2; pB.u4[3] = w3;
#pragma unroll
            for (int icf = 0; icf < 4; ++icf) {
                bf16x8 vf = *(const bf16x8*)(Vt + (size_t)(icf * 32) * NP);
                oacc[icf] = __builtin_amdgcn_mfma_f32_32x32x16_bf16(vf, pB.v, oacc[icf], 0, 0, 0);
            }
        }
        {   // jc=1: keys j0+16..j0+31 from s[8..15]
            u32 w0 = pkbf(s[8], s[9]), w1 = pkbf(s[10], s[11]);
            u32 w2 = pkbf(s[12], s[13]), w3 = pkbf(s[14], s[15]);
            asm("v_permlane32_swap_b32 %0, %1" : "+v"(w0), "+v"(w2));
            asm("v_permlane32_swap_b32 %0, %1" : "+v"(w1), "+v"(w3));
            union { u32 u4[4]; bf16x8 v; } pB;
            pB.u4[0] = w0; pB.u4[1] = w1; pB.u4[2] = w2; pB.u4[3] = w3;
#pragma unroll
            for (int icf = 0; icf < 4; ++icf) {
                bf16x8 vf = *(const bf16x8*)(Vt + (size_t)(icf * 32) * NP + 16);
                oacc[icf] = __builtin_amdgcn_mfma_f32_32x32x16_bf16(vf, pB.v, oacc[icf], 0, 0, 0);
            }
        }
    }

    // ---- in-block merge across the 4 split-waves (bf16 partials) ----
#pragma unroll
    for (int icf = 0; icf < 4; ++icf)
#pragma unroll
        for (int q = 0; q < 16; ++q) {
            const int row = icf * 32 + (q & 3) + 8 * (q >> 2) + 4 * hi;
            Op[w][row][l31] = (__bf16)oacc[icf][q];
        }
    if (hi == 0) { Ml[w][l31] = m; Ll[w][l31] = lsum; }
    __syncthreads();
    {
        const int q = t & 31;
        const int i0g = (t >> 5) * 16;
        const float m0 = Ml[0][q], m1 = Ml[1][q], m2 = Ml[2][q], m3 = Ml[3][q];
        const float ms = fmaxf(fmaxf(m0, m1), fmaxf(m2, m3));
        const float a0 = __expf(m0 - ms), a1 = __expf(m1 - ms);
        const float a2 = __expf(m2 - ms), a3 = __expf(m3 - ms);
        const float den = a0 * Ll[0][q] + a1 * Ll[1][q] + a2 * Ll[2][q] + a3 * Ll[3][q];
        union { __bf16 h[16]; uint4 u4[2]; } pk;
#pragma unroll
        for (int ii = 0; ii < 16; ++ii) {
            const int i = i0g + ii;
            pk.h[ii] = (__bf16)(a0 * (float)Op[0][i][q] + a1 * (float)Op[1][i][q]
                              + a2 * (float)Op[2][i][q] + a3 * (float)Op[3][i][q]);
        }
        const size_t base = ((size_t)((half * 4 + b) * NN) + q0 + q) * CH_ + i0g;
        *(uint4*)&Opart[base] = pk.u4[0];
        *(uint4*)&Opart[base + 8] = pk.u4[1];
        if (t < 32) {
            Mpart[(size_t)(half * 4 + b) * NN + q0 + q] = ms;
            Lpart[(size_t)(half * 4 + b) * NN + q0 + q] = den;
        }
    }
}

// ---------------------------------------------------------------------------
// Merge the 2 KV-half partials -> x0 bf16 pos-major [4][4096][128]
// ---------------------------------------------------------------------------
__global__ __launch_bounds__(256) void attn_merge_kernel(
    const __bf16* __restrict__ Opart, const float* __restrict__ Mpart,
    const float* __restrict__ Lpart, __bf16* __restrict__ x0)
{
    const int id = blockIdx.x * 256 + threadIdx.x;   // 65536
    const int qg = id >> 2;
    const int i0 = (id & 3) * 32;
    const int b = qg >> 12, q = qg & 4095;
    const size_t idx0 = (size_t)b * NN + q;
    const size_t idx1 = (size_t)(4 + b) * NN + q;
    const float m0 = Mpart[idx0], m1 = Mpart[idx1];
    const float ms = fmaxf(m0, m1);
    const float a0 = __expf(m0 - ms), a1 = __expf(m1 - ms);
    const float inv = 1.f / (a0 * Lpart[idx0] + a1 * Lpart[idx1]);
    const __bf16* O0 = &Opart[idx0 * CH_ + i0];
    const __bf16* O1 = &Opart[idx1 * CH_ + i0];
    union { __bf16 h[32]; uint4 u4[4]; } ov;
#pragma unroll
    for (int ii = 0; ii < 32; ++ii)
        ov.h[ii] = (__bf16)((a0 * (float)O0[ii] + a1 * (float)O1[ii]) * inv);
    uint4* dst = (uint4*)&x0[((size_t)b * NN + q) * CH_ + i0];
#pragma unroll
    for (int s = 0; s < 4; ++s) dst[s] = ov.u4[s];
}

// ---------------------------------------------------------------------------
// conv_o (1x1, 128->256) via MFMA + BN + GELU -> Xt0 cols 0-255 (NHWC bf16)
// ---------------------------------------------------------------------------
__global__ __launch_bounds__(256) void convo_mfma_kernel(
    const __bf16* __restrict__ x0, const __bf16* __restrict__ wob,
    const float* __restrict__ bo,
    const float* __restrict__ g, const float* __restrict__ bb,
    const float* __restrict__ mm, const float* __restrict__ vv,
    __bf16* __restrict__ Xt0)
{
    __shared__ float scb[128], shb[128], bsb[128];
    const int t = threadIdx.x;
    const int p0 = blockIdx.x * 128;
    const int o0 = blockIdx.y * 128;
    const int b = blockIdx.z;
    if (t < 128) {
        const int o = o0 + t;
        const float sc = g[o] * rsqrtf(vv[o] + 1e-5f);
        scb[t] = sc; shb[t] = bb[o] - mm[o] * sc; bsb[t] = bo[o];
    }
    __syncthreads();

    const int lane = t & 63, w = t >> 6;
    const int l31 = lane & 31, hi = lane >> 5;
    const int wo2 = w >> 1, wp2 = w & 1;
    const int ob = o0 + wo2 * 64;
    const int pb = p0 + wp2 * 64;

    f32x16 acc[2][2];
#pragma unroll
    for (int i = 0; i < 2; ++i)
#pragma unroll
        for (int j = 0; j < 2; ++j)
#pragma unroll
            for (int e = 0; e < 16; ++e) acc[i][j][e] = 0.f;

#pragma unroll
    for (int kc = 0; kc < 8; ++kc) {
        bf16x8 a0 = *(const bf16x8*)&wob[(size_t)(ob + l31) * 128 + hi * 8 + kc * 16];
        bf16x8 a1 = *(const bf16x8*)&wob[(size_t)(ob + 32 + l31) * 128 + hi * 8 + kc * 16];
        bf16x8 b0 = *(const bf16x8*)&x0[((size_t)(b * NN) + pb + l31) * 128 + hi * 8 + kc * 16];
        bf16x8 b1 = *(const bf16x8*)&x0[((size_t)(b * NN) + pb + 32 + l31) * 128 + hi * 8 + kc * 16];
        acc[0][0] = __builtin_amdgcn_mfma_f32_32x32x16_bf16(a0, b0, acc[0][0], 0, 0, 0);
        acc[0][1] = __builtin_amdgcn_mfma_f32_32x32x16_bf16(a0, b1, acc[0][1], 0, 0, 0);
        acc[1][0] = __builtin_amdgcn_mfma_f32_32x32x16_bf16(a1, b0, acc[1][0], 0, 0, 0);
        acc[1][1] = __builtin_amdgcn_mfma_f32_32x32x16_bf16(a1, b1, acc[1][1], 0, 0, 0);
    }

#pragma unroll
    for (int mi = 0; mi < 2; ++mi)
#pragma unroll
        for (int nx = 0; nx < 2; ++nx) {
            const int p = pb + nx * 32 + l31;
            const size_t rowbase = ((size_t)(b * NN) + p) * 512 + o0;
#pragma unroll
            for (int q4 = 0; q4 < 4; ++q4) {
                const int ol = wo2 * 64 + mi * 32 + q4 * 8 + hi * 4;
                __bf16 pk[4];
#pragma unroll
                for (int j = 0; j < 4; ++j) {
                    float v = acc[mi][nx][q4 * 4 + j] + bsb[ol + j];
                    v = v * scb[ol + j] + shb[ol + j];
                    pk[j] = (__bf16)gelu_erf(v);
                }
                *(uint2*)&Xt0[rowbase + ol] = *(const uint2*)pk;
            }
        }
}

// ---------------------------------------------------------------------------
// 3x3 conv via MFMA (implicit GEMM), NHWC bf16 in/out, BN+GELU. (unchanged)
// ---------------------------------------------------------------------------
template<int IC>
__global__ __launch_bounds__(256) void conv3x3_mfma_kernel(
    const __bf16* __restrict__ Xsrc,   // NHWC [4][4096][IC]
    const __bf16* __restrict__ Wt,     // [9][256][IC]
    const float* __restrict__ bias, const float* __restrict__ bng,
    const float* __restrict__ bnb, const float* __restrict__ bnm,
    const float* __restrict__ bnv,
    __bf16* __restrict__ out)          // NHWC [4][4096][256]
{
    constexpr int NC = IC / 16;
    __shared__ __align__(16) char Wl[2][18432];
    __shared__ __align__(16) char Tl[2][13824];
    __shared__ float scb[64], shb[64], bsb[64];

    const int t = threadIdx.x;
    const int bid = blockIdx.x;
    const int xcd = bid & 7, local = bid >> 3;
    const int combo = xcd * 2 + (local >> 4);
    const int pt = local & 15;
    const int m = combo & 3, b = combo >> 2;
    const int o0 = m * 64;
    const int y0 = pt * 4;

    if (t < 64) {
        const int o = o0 + t;
        const float sc = bng[o] * rsqrtf(bnv[o] + 1e-5f);
        scb[t] = sc; shb[t] = bnb[o] - bnm[o] * sc; bsb[t] = bias[o];
    }

    const int lane = t & 63, w = t >> 6;
    const int l31 = lane & 31, hi = lane >> 5;

    uint4 wreg[5], ireg[3];

    auto loadW = [&](int c0) {
#pragma unroll
        for (int s = 0; s < 5; ++s) {
            int u = t + s * 256;
            if (u < 1152) {
                int g = u & 1, o = (u >> 1) & 63, k9 = u >> 7;
                wreg[s] = *(const uint4*)&Wt[((size_t)(k9 * 256 + o0 + o)) * IC + c0 + g * 8];
            }
        }
    };
    auto loadI = [&](int c0) {
#pragma unroll
        for (int s = 0; s < 3; ++s) {
            int u = t + s * 256;
            int g = u & 1, x = (u >> 1) & 63, r = u >> 7;
            int yy = y0 - 1 + r;
            if (yy >= 0 && yy < 64)
                ireg[s] = *(const uint4*)&Xsrc[((size_t)(b * 4096 + yy * 64 + x)) * IC + c0 + g * 8];
            else
                ireg[s] = make_uint4(0u, 0u, 0u, 0u);
        }
    };
    auto writeW = [&](char* dst) {
#pragma unroll
        for (int s = 0; s < 5; ++s) {
            int u = t + s * 256;
            if (u < 1152) {
                int g = u & 1, o = (u >> 1) & 63, k9 = u >> 7;
                int byte = ((k9 * 64 + o) * 32 + g * 16) ^ ((o & 7) << 4);
                *(uint4*)(dst + byte) = wreg[s];
            }
        }
    };
    auto writeI = [&](char* dst) {
#pragma unroll
        for (int s = 0; s < 3; ++s) {
            int u = t + s * 256;
            int g = u & 1, x = (u >> 1) & 63, r = u >> 7;
            int xh = x + 1;
            int byte = (r * 2304 + xh * 32 + g * 16) ^ ((xh & 7) << 4);
            *(uint4*)(dst + byte) = ireg[s];
        }
        if (t < 24) {
            int g = t & 1, side = (t >> 1) & 1, r = t >> 2;
            int xh = side ? 65 : 0;
            int byte = (r * 2304 + xh * 32 + g * 16) ^ ((xh & 7) << 4);
            *(uint4*)(dst + byte) = make_uint4(0u, 0u, 0u, 0u);
        }
    };

    f32x16 acc[2][2];
#pragma unroll
    for (int i = 0; i < 2; ++i)
#pragma unroll
        for (int j = 0; j < 2; ++j)
#pragma unroll
            for (int e = 0; e < 16; ++e) acc[i][j][e] = 0.f;

    const int Abase = (l31 * 32 + hi * 16) ^ ((l31 & 7) << 4);
    int Bbase[3];
#pragma unroll
    for (int dx = 0; dx < 3; ++dx) {
        int xh = dx + l31;
        Bbase[dx] = (xh * 32 + hi * 16) ^ ((xh & 7) << 4);
    }

    auto compute = [&](const char* Wb, const char* Tb) {
#pragma unroll
        for (int k9 = 0; k9 < 9; ++k9) {
            const int dy = k9 / 3, dx = k9 % 3;
            bf16x8 a0 = *(const bf16x8*)(Wb + k9 * 2048 + Abase);
            bf16x8 a1 = *(const bf16x8*)(Wb + k9 * 2048 + 1024 + Abase);
            const char* Trow = Tb + (w + dy) * 2304;
#pragma unroll
            for (int nx = 0; nx < 2; ++nx) {
                bf16x8 bv = *(const bf16x8*)(Trow + nx * 1024 + Bbase[dx]);
                acc[0][nx] = __builtin_amdgcn_mfma_f32_32x32x16_bf16(a0, bv, acc[0][nx], 0, 0, 0);
                acc[1][nx] = __builtin_amdgcn_mfma_f32_32x32x16_bf16(a1, bv, acc[1][nx], 0, 0, 0);
            }
        }
    };

    loadW(0); loadI(0);
    writeW(Wl[0]); writeI(Tl[0]);
    __syncthreads();
    for (int c = 0; c < NC; ++c) {
        const int cur = c & 1;
        if (c + 1 < NC) { loadW((c + 1) * 16); loadI((c + 1) * 16); }
        compute(Wl[cur], Tl[cur]);
        __syncthreads();
        if (c + 1 < NC) { writeW(Wl[cur ^ 1]); writeI(Tl[cur ^ 1]); }
        __syncthreads();
    }

#pragma unroll
    for (int mi = 0; mi < 2; ++mi)
#pragma unroll
        for (int nx = 0; nx < 2; ++nx) {
            const int x = nx * 32 + l31;
            const int p = (y0 + w) * 64 + x;
            const size_t rowbase = ((size_t)(b * 4096 + p)) * 256 + o0;
#pragma unroll
            for (int q = 0; q < 4; ++q) {
                const int obase = mi * 32 + q * 8 + hi * 4;
                __bf16 pk[4];
#pragma unroll
                for (int j = 0; j < 4; ++j) {
                    float v = acc[mi][nx][q * 4 + j] + bsb[obase + j];
                    v = v * scb[obase + j] + shb[obase + j];
                    pk[j] = (__bf16)gelu_erf(v);
                }
                *(uint2*)&out[rowbase + obase] = *(const uint2*)pk;
            }
        }
}

// ---------------------------------------------------------------------------
// global max of (y1 + x0gelu) over spatial, two stages
// ---------------------------------------------------------------------------
__global__ __launch_bounds__(256) void maxpart_kernel(
    const __bf16* __restrict__ y1, const __bf16* __restrict__ xt0,
    float* __restrict__ part)
{
    const int o = threadIdx.x;
    const int chunk = blockIdx.x & 63;
    const int b = blockIdx.x >> 6;
    float mx = -1e30f;
    for (int pp = 0; pp < 64; ++pp) {
        int p = chunk * 64 + pp;
        float a = (float)y1[((size_t)(b * 4096 + p)) * 256 + o];
        float c = (float)xt0[((size_t)(b * 4096 + p)) * 512 + o];
        mx = fmaxf(mx, a + c);
    }
    part[((size_t)(b * 64 + chunk)) * 256 + o] = mx;
}

__global__ __launch_bounds__(256) void maxfin_kernel(
    const float* __restrict__ part, float* __restrict__ out)
{
    const int o = threadIdx.x;
    const int b = blockIdx.x;
    float mx = -1e30f;
    for (int c = 0; c < 64; ++c)
        mx = fmaxf(mx, part[((size_t)(b * 64 + c)) * 256 + o]);
    out[b * 256 + o] = mx;
}

// ---------------------------------------------------------------------------
extern "C" void kernel_launch(void* const* d_in, const int* in_sizes, int n_in,
                              void* d_out, int out_size, void* d_ws, size_t ws_size,
                              hipStream_t stream)
{
    const float* in0  = (const float*)d_in[0];
    const float* in1  = (const float*)d_in[1];
    const float* w_q  = (const float*)d_in[2];
    const float* b_q  = (const float*)d_in[3];
    const float* w_k  = (const float*)d_in[4];
    const float* b_k  = (const float*)d_in[5];
    const float* w_v  = (const float*)d_in[6];
    const float* b_v  = (const float*)d_in[7];
    const float* w_o  = (const float*)d_in[8];
    const float* b_o  = (const float*)d_in[9];
    const float* bn0g = (const float*)d_in[10];
    const float* bn0b = (const float*)d_in[11];
    const float* bn0m = (const float*)d_in[12];
    const float* bn0v = (const float*)d_in[13];
    const float* cbw0 = (const float*)d_in[14];
    const float* cbb0 = (const float*)d_in[15];
    const float* cb0g = (const float*)d_in[16];
    const float* cb0b = (const float*)d_in[17];
    const float* cb0m = (const float*)d_in[18];
    const float* cb0v = (const float*)d_in[19];
    const float* cbw1 = (const float*)d_in[20];
    const float* cbb1 = (const float*)d_in[21];
    const float* cb1g = (const float*)d_in[22];
    const float* cb1b = (const float*)d_in[23];
    const float* cb1m = (const float*)d_in[24];
    const float* cb1v = (const float*)d_in[25];

    char* wsb = (char*)d_ws;
    const size_t MB = 1u << 20;
    __bf16* Xt0  = (__bf16*)(wsb);
    __bf16* Xin1 = (__bf16*)(wsb + 16 * MB);
    __bf16* Opart= (__bf16*)(wsb + 16 * MB);
    __bf16* Qpm  = (__bf16*)(wsb + 24 * MB);
    __bf16* x0   = (__bf16*)(wsb + 24 * MB);
    __bf16* Kpm  = (__bf16*)(wsb + 28 * MB);
    __bf16* y0   = (__bf16*)(wsb + 24 * MB);
    __bf16* Vcm  = (__bf16*)(wsb + 32 * MB);
    __bf16* y1   = (__bf16*)(wsb + 32 * MB);
    __bf16* wqb  = (__bf16*)(wsb + 40 * MB);
    __bf16* wkb  = (__bf16*)(wsb + 40 * MB + 65536);
    __bf16* wvb  = (__bf16*)(wsb + 40 * MB + 2 * 65536);
    __bf16* wob  = (__bf16*)(wsb + 40 * MB + 3 * 65536);
    __bf16* Wt0  = (__bf16*)(wsb + 40 * MB + 4 * 65536);              // 2359296 B
    __bf16* Wt1  = (__bf16*)(wsb + 40 * MB + 4 * 65536 + 2359296);    // 1179648 B
    float*  Mpart= (float*)(wsb + 44 * MB);                            // 128KB
    float*  Lpart= (float*)(wsb + 44 * MB + 131072);                   // 128KB
    float*  part = (float*)(wsb + 44 * MB + 2 * 131072);               // 256KB
    float* outp = (float*)d_out;

    nhwc_cast_kernel<<<dim3(64, 4, 4), 256, 0, stream>>>(in0, Xt0, 256, 512);
    nhwc_cast_kernel<<<dim3(64, 4, 4), 256, 0, stream>>>(in1, Xin1, 0, 256);
    wtrans_kernel<<<1280, 256, 0, stream>>>(cbw0, cbw1, w_q, w_k, w_v, w_o,
                                            Wt0, Wt1, wqb, wkb, wvb, wob);
    proj_mfma_kernel<<<dim3(32, 1, 12), 256, 0, stream>>>(
        Xt0, Xin1, wqb, wkb, wvb, b_q, b_k, b_v, Vcm, Kpm, Qpm);
    attn_mfma_kernel<<<1024, 256, 0, stream>>>(Qpm, Kpm, Vcm, Opart, Mpart, Lpart);
    attn_merge_kernel<<<256, 256, 0, stream>>>(Opart, Mpart, Lpart, x0);
    convo_mfma_kernel<<<dim3(32, 2, 4), 256, 0, stream>>>(
        x0, wob, b_o, bn0g, bn0b, bn0m, bn0v, Xt0);
    conv3x3_mfma_kernel<512><<<256, 256, 0, stream>>>(Xt0, Wt0, cbb0, cb0g, cb0b, cb0m, cb0v, y0);
    conv3x3_mfma_kernel<256><<<256, 256, 0, stream>>>(y0, Wt1, cbb1, cb1g, cb1b, cb1m, cb1v, y1);
    maxpart_kernel<<<256, 256, 0, stream>>>(y1, Xt0, part);
    maxfin_kernel<<<4, 256, 0, stream>>>(part, outp);
}

// Round 8
// 306.009 us; speedup vs baseline: 1.2228x; 1.2144x over previous
//
#include <hip/hip_runtime.h>
#include <math.h>

#define B_ 4
#define C_ 256
#define CH_ 128
#define NN 4096   // H*W = 64*64

typedef __bf16 bf16x8 __attribute__((ext_vector_type(8)));
typedef float f32x16 __attribute__((ext_vector_type(16)));
typedef unsigned int u32;

__device__ __forceinline__ float gelu_erf(float x) {
    return 0.5f * x * (1.0f + erff(x * 0.7071067811865476f));
}

__device__ __forceinline__ u32 pkbf(float a, float b) {
    union { __bf16 h[2]; u32 u; } x;
    x.h[0] = (__bf16)a; x.h[1] = (__bf16)b;
    return x.u;
}

// ---------------------------------------------------------------------------
// NCHW fp32 -> NHWC bf16 cast/transpose.
// ---------------------------------------------------------------------------
__global__ __launch_bounds__(256) void nhwc_cast_kernel(
    const float* __restrict__ src, __bf16* __restrict__ dst,
    int colbase, int rowstride)
{
    __shared__ float Lt[64][65];
    const int t = threadIdx.x;
    const int p0 = blockIdx.x * 64;
    const int c0 = blockIdx.y * 64;
    const int b  = blockIdx.z;
#pragma unroll
    for (int i = 0; i < 16; ++i) {
        int idx = t + i * 256;
        int c = idx >> 6, p = idx & 63;
        Lt[c][p] = src[((size_t)(b * 256 + c0 + c)) * 4096 + p0 + p];
    }
    __syncthreads();
#pragma unroll
    for (int i = 0; i < 16; ++i) {
        int idx = t + i * 256;
        int p = idx >> 6, c = idx & 63;
        dst[((size_t)(b * 4096 + p0 + p)) * rowstride + colbase + c0 + c] = (__bf16)Lt[c][p];
    }
}

// ---------------------------------------------------------------------------
// Weight transform: conv3x3 weights -> [k9][O][I] bf16; 1x1 weights -> bf16 copy
// ---------------------------------------------------------------------------
__global__ __launch_bounds__(256) void wtrans_kernel(
    const float* __restrict__ w0, const float* __restrict__ w1,
    const float* __restrict__ wq, const float* __restrict__ wk,
    const float* __restrict__ wv, const float* __restrict__ wo,
    __bf16* __restrict__ Wt0, __bf16* __restrict__ Wt1,
    __bf16* __restrict__ wqb, __bf16* __restrict__ wkb,
    __bf16* __restrict__ wvb, __bf16* __restrict__ wob)
{
    int id = blockIdx.x * 256 + threadIdx.x;
    if (id < 131072) {
        int o = id >> 9, ci = id & 511;
        const float* s = w0 + (size_t)id * 9;
#pragma unroll
        for (int k = 0; k < 9; ++k)
            Wt0[((size_t)k * 256 + o) * 512 + ci] = (__bf16)s[k];
    } else if (id < 196608) {
        int id2 = id - 131072;
        int o = id2 >> 8, ci = id2 & 255;
        const float* s = w1 + (size_t)id2 * 9;
#pragma unroll
        for (int k = 0; k < 9; ++k)
            Wt1[((size_t)k * 256 + o) * 256 + ci] = (__bf16)s[k];
    } else {
        int id3 = id - 196608;     // 0..131071
        int sel = id3 >> 15;
        int k = id3 & 32767;
        const float* s = sel == 0 ? wq : sel == 1 ? wk : sel == 2 ? wv : wo;
        __bf16* d = sel == 0 ? wqb : sel == 1 ? wkb : sel == 2 ? wvb : wob;
        d[k] = (__bf16)s[k];
    }
}

// ---------------------------------------------------------------------------
// 1x1 projections via MFMA, outputs in MFMA-FRAGMENT-MAJOR order so the
// attention hot loop's loads are lane-contiguous (base + lane*16B):
//   Q/K: frag[tile(32 pos)][ic(8)][lane(64)][8 ch]   (A/B operand of QK^T)
//   V:   frag[tile(32 key)][jc(2)][icf(4)][lane(64)][8 key]  (A operand of PV)
// which: 0 -> V (w_q on in0), 1 -> K (w_k on in0), 2 -> Q (w_v on in1)
// ---------------------------------------------------------------------------
__global__ __launch_bounds__(256) void proj_mfma_kernel(
    const __bf16* __restrict__ Xt0,   // [4][4096][512], in0 at cols 256-511
    const __bf16* __restrict__ Xin1,  // [4][4096][256]
    const __bf16* __restrict__ wqb, const __bf16* __restrict__ wkb,
    const __bf16* __restrict__ wvb,
    const float* __restrict__ bq, const float* __restrict__ bk,
    const float* __restrict__ bv,
    __bf16* __restrict__ Vswz, __bf16* __restrict__ Kswz, __bf16* __restrict__ Qswz)
{
    __shared__ __align__(16) __bf16 Vt[4][64][80];
    __shared__ float biasl[128];

    const int t = threadIdx.x;
    const int which = blockIdx.z % 3;
    const int b = blockIdx.z / 3;
    const int p0 = blockIdx.x * 128;

    const __bf16* W = which == 0 ? wqb : which == 1 ? wkb : wvb;
    const float* bias = which == 0 ? bq : which == 1 ? bk : bv;
    const __bf16* src; int stride, colb;
    if (which == 2) { src = Xin1 + (size_t)b * NN * 256; stride = 256; colb = 0; }
    else            { src = Xt0  + (size_t)b * NN * 512; stride = 512; colb = 256; }

    if (t < 128) biasl[t] = bias[t];
    __syncthreads();

    const int lane = t & 63, w = t >> 6;
    const int l31 = lane & 31, hi = lane >> 5;
    const int wo2 = w >> 1, wp2 = w & 1;
    const int ob = wo2 * 64;
    const int pb = p0 + wp2 * 64;

    f32x16 acc[2][2];
#pragma unroll
    for (int i = 0; i < 2; ++i)
#pragma unroll
        for (int j = 0; j < 2; ++j)
#pragma unroll
            for (int e = 0; e < 16; ++e) acc[i][j][e] = 0.f;

#pragma unroll
    for (int kc = 0; kc < 16; ++kc) {
        bf16x8 a0 = *(const bf16x8*)&W[(size_t)(ob + l31) * 256 + hi * 8 + kc * 16];
        bf16x8 a1 = *(const bf16x8*)&W[(size_t)(ob + 32 + l31) * 256 + hi * 8 + kc * 16];
        bf16x8 b0 = *(const bf16x8*)&src[(size_t)(pb + l31) * stride + colb + hi * 8 + kc * 16];
        bf16x8 b1 = *(const bf16x8*)&src[(size_t)(pb + 32 + l31) * stride + colb + hi * 8 + kc * 16];
        acc[0][0] = __builtin_amdgcn_mfma_f32_32x32x16_bf16(a0, b0, acc[0][0], 0, 0, 0);
        acc[0][1] = __builtin_amdgcn_mfma_f32_32x32x16_bf16(a0, b1, acc[0][1], 0, 0, 0);
        acc[1][0] = __builtin_amdgcn_mfma_f32_32x32x16_bf16(a1, b0, acc[1][0], 0, 0, 0);
        acc[1][1] = __builtin_amdgcn_mfma_f32_32x32x16_bf16(a1, b1, acc[1][1], 0, 0, 0);
    }

    if (which) {
        // Q/K fragment-major store. Value acc[mi][nx][q4*4+j]:
        //   pos p = pb + nx*32 + l31, ch = ob + mi*32 + q4*8 + hi*4 + j
        //   -> tile = (pb>>5)+nx, ic = (ob>>4)+mi*2+(q4>>1), lane' = l31+32*(q4&1),
        //      byte = lane'*16 + hi*8
        __bf16* dst = (which == 1 ? Kswz : Qswz) + (size_t)b * NN * CH_;
#pragma unroll
        for (int mi = 0; mi < 2; ++mi)
#pragma unroll
            for (int nx = 0; nx < 2; ++nx) {
                const int tile = (pb >> 5) + nx;
#pragma unroll
                for (int q4 = 0; q4 < 4; ++q4) {
                    const int ic = (ob >> 4) + mi * 2 + (q4 >> 1);
                    const int og = ob + mi * 32 + q4 * 8 + hi * 4;
                    __bf16 pk[4];
#pragma unroll
                    for (int j = 0; j < 4; ++j)
                        pk[j] = (__bf16)(acc[mi][nx][q4 * 4 + j] + biasl[og + j]);
                    const size_t el = ((size_t)(tile * 8 + ic) * 64
                                       + l31 + 32 * (q4 & 1)) * 8 + hi * 4;
                    *(uint2*)&dst[el] = *(const uint2*)pk;
                }
            }
    } else {
        // V: transpose through LDS, then fragment-major store
#pragma unroll
        for (int mi = 0; mi < 2; ++mi)
#pragma unroll
            for (int nx = 0; nx < 2; ++nx) {
                const int ploc = nx * 32 + l31;
#pragma unroll
                for (int q4 = 0; q4 < 4; ++q4) {
                    const int oloc = mi * 32 + q4 * 8 + hi * 4;
#pragma unroll
                    for (int j = 0; j < 4; ++j)
                        Vt[w][oloc + j][ploc] =
                            (__bf16)(acc[mi][nx][q4 * 4 + j] + biasl[ob + oloc + j]);
                }
            }
        __syncthreads();
        // wave covers ch ob..ob+63, pos pb..pb+63.
        // Fragment (tile,jc,icf): lane (l31,hi) holds V[icf*32+l31][tile*32+jc*16+hi*8 ..+7]
        __bf16* dst = Vswz + (size_t)b * NN * CH_;
#pragma unroll
        for (int s = 0; s < 8; ++s) {
            const int tl = s >> 2, jc = (s >> 1) & 1, il = s & 1;
            const int tile_g = (pb >> 5) + tl;
            const int icf_g = (ob >> 5) + il;
            const int i_loc = il * 32 + l31;
            const int kk = tl * 32 + jc * 16 + hi * 8;
            uint4 v = *(const uint4*)&Vt[w][i_loc][kk];
            const size_t el = ((size_t)((tile_g * 2 + jc) * 4 + icf_g) * 64 + lane) * 8;
            *(uint4*)&dst[el] = v;
        }
    }
}

// ---------------------------------------------------------------------------
// MFMA bf16 flash attention. All hot-loop loads are fragment-major
// (base + lane*16B, fully coalesced — R7 was TA/gather-bound with 32-line
// scatters per load). Logic unchanged from the verified R7 kernel.
// grid 1024, block 256 (4 waves x KV-split-8 with 2 block-halves).
// ---------------------------------------------------------------------------
__global__ __launch_bounds__(256, 4) void attn_mfma_kernel(
    const __bf16* __restrict__ Qswz, const __bf16* __restrict__ Kswz,
    const __bf16* __restrict__ Vswz,
    __bf16* __restrict__ Opart, float* __restrict__ Mpart, float* __restrict__ Lpart)
{
    __shared__ __bf16 Op[4][128][34];   // 34816 B
    __shared__ float Ml[4][32], Ll[4][32];

    const int t = threadIdx.x;
    const int lane = t & 63;
    const int w = t >> 6;
    const int l31 = lane & 31;
    const int hi = lane >> 5;

    const int bid = blockIdx.x;
    const int xcd = bid & 7;
    const int b = xcd >> 1;                      // 2 XCDs per batch
    const int local = bid >> 3;                  // 0..127
    const int qt = (xcd & 1) * 64 + (local & 63);
    const int half = local >> 6;
    const int q0 = qt * 32;

    // Q B-fragments (coalesced: tile qt, 8 ic chunks)
    const __bf16* Qs = Qswz + (size_t)b * NN * CH_ + (size_t)qt * 4096 + lane * 8;
    bf16x8 qf[8];
#pragma unroll
    for (int ic = 0; ic < 8; ++ic) qf[ic] = *(const bf16x8*)(Qs + ic * 512);

    const __bf16* Ks = Kswz + (size_t)b * NN * CH_ + lane * 8;
    const __bf16* Vs = Vswz + (size_t)b * NN * CH_ + lane * 8;

    f32x16 oacc[4];
#pragma unroll
    for (int i = 0; i < 4; ++i)
#pragma unroll
        for (int e = 0; e < 16; ++e) oacc[i][e] = 0.f;

    float m = -3e38f, lsum = 0.f;
    const int tbase = half * 64 + w * 16;   // 16 key-tiles of 32 per wave

    for (int jt = 0; jt < 16; ++jt) {
        const int tile = tbase + jt;
        // ---- QK^T: S[j=32 keys][k=32 queries] ----
        f32x16 s;
#pragma unroll
        for (int e = 0; e < 16; ++e) s[e] = 0.f;
        const __bf16* Kt = Ks + (size_t)tile * 4096;
#pragma unroll
        for (int ic = 0; ic < 8; ++ic) {
            bf16x8 kf = *(const bf16x8*)(Kt + ic * 512);
            s = __builtin_amdgcn_mfma_f32_32x32x16_bf16(kf, qf[ic], s, 0, 0, 0);
        }
        // ---- tile max (in-lane tree + shfl cross-half) ----
        float t8[8];
#pragma unroll
        for (int e = 0; e < 8; ++e) t8[e] = fmaxf(s[e], s[e + 8]);
#pragma unroll
        for (int e = 0; e < 4; ++e) t8[e] = fmaxf(t8[e], t8[e + 4]);
        t8[0] = fmaxf(t8[0], t8[2]); t8[1] = fmaxf(t8[1], t8[3]);
        float mu = fmaxf(t8[0], t8[1]);
        const float pm = fmaxf(mu, __shfl_xor(mu, 32));
        // ---- defer-max rescale ----
        if (!__all(pm <= m + 8.f)) {
            const float mn = fmaxf(m, pm);
            const float al = __expf(m - mn);
            m = mn;
            lsum *= al;
#pragma unroll
            for (int i = 0; i < 4; ++i)
#pragma unroll
                for (int e = 0; e < 16; ++e) oacc[i][e] *= al;
        }
        // ---- exp + tile sum ----
#pragma unroll
        for (int e = 0; e < 16; ++e) s[e] = __expf(s[e] - m);
        float s8[8];
#pragma unroll
        for (int e = 0; e < 8; ++e) s8[e] = s[e] + s[e + 8];
#pragma unroll
        for (int e = 0; e < 4; ++e) s8[e] += s8[e + 4];
        s8[0] += s8[2]; s8[1] += s8[3];
        float su = s8[0] + s8[1];
        lsum += su + __shfl_xor(su, 32);

        // ---- pack P->bf16 B-frags via permlane32_swap, PV per 16-key chunk ----
        const __bf16* Vt = Vs + (size_t)tile * 4096;
        {   // jc=0: keys tile*32 .. +15 from s[0..7]
            u32 w0 = pkbf(s[0], s[1]), w1 = pkbf(s[2], s[3]);
            u32 w2 = pkbf(s[4], s[5]), w3 = pkbf(s[6], s[7]);
            asm("v_permlane32_swap_b32 %0, %1" : "+v"(w0), "+v"(w2));
            asm("v_permlane32_swap_b32 %0, %1" : "+v"(w1), "+v"(w3));
            union { u32 u4[4]; bf16x8 v; } pB;
            pB.u4[0] = w0; pB.u4[1] = w1; pB.u4[2] = w2; pB.u4[3] = w3;
#pragma unroll
            for (int icf = 0; icf < 4; ++icf) {
                bf16x8 vf = *(const bf16x8*)(Vt + icf * 512);
                oacc[icf] = __builtin_amdgcn_mfma_f32_32x32x16_bf16(vf, pB.v, oacc[icf], 0, 0, 0);
            }
        }
        {   // jc=1: keys tile*32+16 .. +31 from s[8..15]
            u32 w0 = pkbf(s[8], s[9]), w1 = pkbf(s[10], s[11]);
            u32 w2 = pkbf(s[12], s[13]), w3 = pkbf(s[14], s[15]);
            asm("v_permlane32_swap_b32 %0, %1" : "+v"(w0), "+v"(w2));
            asm("v_permlane32_swap_b32 %0, %1" : "+v"(w1), "+v"(w3));
            union { u32 u4[4]; bf16x8 v; } pB;
            pB.u4[0] = w0; pB.u4[1] = w1; pB.u4[2] = w2; pB.u4[3] = w3;
#pragma unroll
            for (int icf = 0; icf < 4; ++icf) {
                bf16x8 vf = *(const bf16x8*)(Vt + 2048 + icf * 512);
                oacc[icf] = __builtin_amdgcn_mfma_f32_32x32x16_bf16(vf, pB.v, oacc[icf], 0, 0, 0);
            }
        }
    }

    // ---- in-block merge across the 4 split-waves (bf16 partials) ----
#pragma unroll
    for (int icf = 0; icf < 4; ++icf)
#pragma unroll
        for (int q = 0; q < 16; ++q) {
            const int row = icf * 32 + (q & 3) + 8 * (q >> 2) + 4 * hi;
            Op[w][row][l31] = (__bf16)oacc[icf][q];
        }
    if (hi == 0) { Ml[w][l31] = m; Ll[w][l31] = lsum; }
    __syncthreads();
    {
        const int q = t & 31;
        const int i0g = (t >> 5) * 16;
        const float m0 = Ml[0][q], m1 = Ml[1][q], m2 = Ml[2][q], m3 = Ml[3][q];
        const float ms = fmaxf(fmaxf(m0, m1), fmaxf(m2, m3));
        const float a0 = __expf(m0 - ms), a1 = __expf(m1 - ms);
        const float a2 = __expf(m2 - ms), a3 = __expf(m3 - ms);
        const float den = a0 * Ll[0][q] + a1 * Ll[1][q] + a2 * Ll[2][q] + a3 * Ll[3][q];
        union { __bf16 h[16]; uint4 u4[2]; } pk;
#pragma unroll
        for (int ii = 0; ii < 16; ++ii) {
            const int i = i0g + ii;
            pk.h[ii] = (__bf16)(a0 * (float)Op[0][i][q] + a1 * (float)Op[1][i][q]
                              + a2 * (float)Op[2][i][q] + a3 * (float)Op[3][i][q]);
        }
        const size_t base = ((size_t)((half * 4 + b) * NN) + q0 + q) * CH_ + i0g;
        *(uint4*)&Opart[base] = pk.u4[0];
        *(uint4*)&Opart[base + 8] = pk.u4[1];
        if (t < 32) {
            Mpart[(size_t)(half * 4 + b) * NN + q0 + q] = ms;
            Lpart[(size_t)(half * 4 + b) * NN + q0 + q] = den;
        }
    }
}

// ---------------------------------------------------------------------------
// Merge the 2 KV-half partials -> x0 bf16 pos-major [4][4096][128]
// ---------------------------------------------------------------------------
__global__ __launch_bounds__(256) void attn_merge_kernel(
    const __bf16* __restrict__ Opart, const float* __restrict__ Mpart,
    const float* __restrict__ Lpart, __bf16* __restrict__ x0)
{
    const int id = blockIdx.x * 256 + threadIdx.x;   // 65536
    const int qg = id >> 2;
    const int i0 = (id & 3) * 32;
    const int b = qg >> 12, q = qg & 4095;
    const size_t idx0 = (size_t)b * NN + q;
    const size_t idx1 = (size_t)(4 + b) * NN + q;
    const float m0 = Mpart[idx0], m1 = Mpart[idx1];
    const float ms = fmaxf(m0, m1);
    const float a0 = __expf(m0 - ms), a1 = __expf(m1 - ms);
    const float inv = 1.f / (a0 * Lpart[idx0] + a1 * Lpart[idx1]);
    const __bf16* O0 = &Opart[idx0 * CH_ + i0];
    const __bf16* O1 = &Opart[idx1 * CH_ + i0];
    union { __bf16 h[32]; uint4 u4[4]; } ov;
#pragma unroll
    for (int ii = 0; ii < 32; ++ii)
        ov.h[ii] = (__bf16)((a0 * (float)O0[ii] + a1 * (float)O1[ii]) * inv);
    uint4* dst = (uint4*)&x0[((size_t)b * NN + q) * CH_ + i0];
#pragma unroll
    for (int s = 0; s < 4; ++s) dst[s] = ov.u4[s];
}

// ---------------------------------------------------------------------------
// conv_o (1x1, 128->256) via MFMA + BN + GELU -> Xt0 cols 0-255 (NHWC bf16)
// ---------------------------------------------------------------------------
__global__ __launch_bounds__(256) void convo_mfma_kernel(
    const __bf16* __restrict__ x0, const __bf16* __restrict__ wob,
    const float* __restrict__ bo,
    const float* __restrict__ g, const float* __restrict__ bb,
    const float* __restrict__ mm, const float* __restrict__ vv,
    __bf16* __restrict__ Xt0)
{
    __shared__ float scb[128], shb[128], bsb[128];
    const int t = threadIdx.x;
    const int p0 = blockIdx.x * 128;
    const int o0 = blockIdx.y * 128;
    const int b = blockIdx.z;
    if (t < 128) {
        const int o = o0 + t;
        const float sc = g[o] * rsqrtf(vv[o] + 1e-5f);
        scb[t] = sc; shb[t] = bb[o] - mm[o] * sc; bsb[t] = bo[o];
    }
    __syncthreads();

    const int lane = t & 63, w = t >> 6;
    const int l31 = lane & 31, hi = lane >> 5;
    const int wo2 = w >> 1, wp2 = w & 1;
    const int ob = o0 + wo2 * 64;
    const int pb = p0 + wp2 * 64;

    f32x16 acc[2][2];
#pragma unroll
    for (int i = 0; i < 2; ++i)
#pragma unroll
        for (int j = 0; j < 2; ++j)
#pragma unroll
            for (int e = 0; e < 16; ++e) acc[i][j][e] = 0.f;

#pragma unroll
    for (int kc = 0; kc < 8; ++kc) {
        bf16x8 a0 = *(const bf16x8*)&wob[(size_t)(ob + l31) * 128 + hi * 8 + kc * 16];
        bf16x8 a1 = *(const bf16x8*)&wob[(size_t)(ob + 32 + l31) * 128 + hi * 8 + kc * 16];
        bf16x8 b0 = *(const bf16x8*)&x0[((size_t)(b * NN) + pb + l31) * 128 + hi * 8 + kc * 16];
        bf16x8 b1 = *(const bf16x8*)&x0[((size_t)(b * NN) + pb + 32 + l31) * 128 + hi * 8 + kc * 16];
        acc[0][0] = __builtin_amdgcn_mfma_f32_32x32x16_bf16(a0, b0, acc[0][0], 0, 0, 0);
        acc[0][1] = __builtin_amdgcn_mfma_f32_32x32x16_bf16(a0, b1, acc[0][1], 0, 0, 0);
        acc[1][0] = __builtin_amdgcn_mfma_f32_32x32x16_bf16(a1, b0, acc[1][0], 0, 0, 0);
        acc[1][1] = __builtin_amdgcn_mfma_f32_32x32x16_bf16(a1, b1, acc[1][1], 0, 0, 0);
    }

#pragma unroll
    for (int mi = 0; mi < 2; ++mi)
#pragma unroll
        for (int nx = 0; nx < 2; ++nx) {
            const int p = pb + nx * 32 + l31;
            const size_t rowbase = ((size_t)(b * NN) + p) * 512 + o0;
#pragma unroll
            for (int q4 = 0; q4 < 4; ++q4) {
                const int ol = wo2 * 64 + mi * 32 + q4 * 8 + hi * 4;
                __bf16 pk[4];
#pragma unroll
                for (int j = 0; j < 4; ++j) {
                    float v = acc[mi][nx][q4 * 4 + j] + bsb[ol + j];
                    v = v * scb[ol + j] + shb[ol + j];
                    pk[j] = (__bf16)gelu_erf(v);
                }
                *(uint2*)&Xt0[rowbase + ol] = *(const uint2*)pk;
            }
        }
}

// ---------------------------------------------------------------------------
// 3x3 conv via MFMA (implicit GEMM), NHWC bf16 in/out, BN+GELU. (unchanged)
// ---------------------------------------------------------------------------
template<int IC>
__global__ __launch_bounds__(256) void conv3x3_mfma_kernel(
    const __bf16* __restrict__ Xsrc,   // NHWC [4][4096][IC]
    const __bf16* __restrict__ Wt,     // [9][256][IC]
    const float* __restrict__ bias, const float* __restrict__ bng,
    const float* __restrict__ bnb, const float* __restrict__ bnm,
    const float* __restrict__ bnv,
    __bf16* __restrict__ out)          // NHWC [4][4096][256]
{
    constexpr int NC = IC / 16;
    __shared__ __align__(16) char Wl[2][18432];
    __shared__ __align__(16) char Tl[2][13824];
    __shared__ float scb[64], shb[64], bsb[64];

    const int t = threadIdx.x;
    const int bid = blockIdx.x;
    const int xcd = bid & 7, local = bid >> 3;
    const int combo = xcd * 2 + (local >> 4);
    const int pt = local & 15;
    const int m = combo & 3, b = combo >> 2;
    const int o0 = m * 64;
    const int y0 = pt * 4;

    if (t < 64) {
        const int o = o0 + t;
        const float sc = bng[o] * rsqrtf(bnv[o] + 1e-5f);
        scb[t] = sc; shb[t] = bnb[o] - bnm[o] * sc; bsb[t] = bias[o];
    }

    const int lane = t & 63, w = t >> 6;
    const int l31 = lane & 31, hi = lane >> 5;

    uint4 wreg[5], ireg[3];

    auto loadW = [&](int c0) {
#pragma unroll
        for (int s = 0; s < 5; ++s) {
            int u = t + s * 256;
            if (u < 1152) {
                int g = u & 1, o = (u >> 1) & 63, k9 = u >> 7;
                wreg[s] = *(const uint4*)&Wt[((size_t)(k9 * 256 + o0 + o)) * IC + c0 + g * 8];
            }
        }
    };
    auto loadI = [&](int c0) {
#pragma unroll
        for (int s = 0; s < 3; ++s) {
            int u = t + s * 256;
            int g = u & 1, x = (u >> 1) & 63, r = u >> 7;
            int yy = y0 - 1 + r;
            if (yy >= 0 && yy < 64)
                ireg[s] = *(const uint4*)&Xsrc[((size_t)(b * 4096 + yy * 64 + x)) * IC + c0 + g * 8];
            else
                ireg[s] = make_uint4(0u, 0u, 0u, 0u);
        }
    };
    auto writeW = [&](char* dst) {
#pragma unroll
        for (int s = 0; s < 5; ++s) {
            int u = t + s * 256;
            if (u < 1152) {
                int g = u & 1, o = (u >> 1) & 63, k9 = u >> 7;
                int byte = ((k9 * 64 + o) * 32 + g * 16) ^ ((o & 7) << 4);
                *(uint4*)(dst + byte) = wreg[s];
            }
        }
    };
    auto writeI = [&](char* dst) {
#pragma unroll
        for (int s = 0; s < 3; ++s) {
            int u = t + s * 256;
            int g = u & 1, x = (u >> 1) & 63, r = u >> 7;
            int xh = x + 1;
            int byte = (r * 2304 + xh * 32 + g * 16) ^ ((xh & 7) << 4);
            *(uint4*)(dst + byte) = ireg[s];
        }
        if (t < 24) {
            int g = t & 1, side = (t >> 1) & 1, r = t >> 2;
            int xh = side ? 65 : 0;
            int byte = (r * 2304 + xh * 32 + g * 16) ^ ((xh & 7) << 4);
            *(uint4*)(dst + byte) = make_uint4(0u, 0u, 0u, 0u);
        }
    };

    f32x16 acc[2][2];
#pragma unroll
    for (int i = 0; i < 2; ++i)
#pragma unroll
        for (int j = 0; j < 2; ++j)
#pragma unroll
            for (int e = 0; e < 16; ++e) acc[i][j][e] = 0.f;

    const int Abase = (l31 * 32 + hi * 16) ^ ((l31 & 7) << 4);
    int Bbase[3];
#pragma unroll
    for (int dx = 0; dx < 3; ++dx) {
        int xh = dx + l31;
        Bbase[dx] = (xh * 32 + hi * 16) ^ ((xh & 7) << 4);
    }

    auto compute = [&](const char* Wb, const char* Tb) {
#pragma unroll
        for (int k9 = 0; k9 < 9; ++k9) {
            const int dy = k9 / 3, dx = k9 % 3;
            bf16x8 a0 = *(const bf16x8*)(Wb + k9 * 2048 + Abase);
            bf16x8 a1 = *(const bf16x8*)(Wb + k9 * 2048 + 1024 + Abase);
            const char* Trow = Tb + (w + dy) * 2304;
#pragma unroll
            for (int nx = 0; nx < 2; ++nx) {
                bf16x8 bv = *(const bf16x8*)(Trow + nx * 1024 + Bbase[dx]);
                acc[0][nx] = __builtin_amdgcn_mfma_f32_32x32x16_bf16(a0, bv, acc[0][nx], 0, 0, 0);
                acc[1][nx] = __builtin_amdgcn_mfma_f32_32x32x16_bf16(a1, bv, acc[1][nx], 0, 0, 0);
            }
        }
    };

    loadW(0); loadI(0);
    writeW(Wl[0]); writeI(Tl[0]);
    __syncthreads();
    for (int c = 0; c < NC; ++c) {
        const int cur = c & 1;
        if (c + 1 < NC) { loadW((c + 1) * 16); loadI((c + 1) * 16); }
        compute(Wl[cur], Tl[cur]);
        __syncthreads();
        if (c + 1 < NC) { writeW(Wl[cur ^ 1]); writeI(Tl[cur ^ 1]); }
        __syncthreads();
    }

#pragma unroll
    for (int mi = 0; mi < 2; ++mi)
#pragma unroll
        for (int nx = 0; nx < 2; ++nx) {
            const int x = nx * 32 + l31;
            const int p = (y0 + w) * 64 + x;
            const size_t rowbase = ((size_t)(b * 4096 + p)) * 256 + o0;
#pragma unroll
            for (int q = 0; q < 4; ++q) {
                const int obase = mi * 32 + q * 8 + hi * 4;
                __bf16 pk[4];
#pragma unroll
                for (int j = 0; j < 4; ++j) {
                    float v = acc[mi][nx][q * 4 + j] + bsb[obase + j];
                    v = v * scb[obase + j] + shb[obase + j];
                    pk[j] = (__bf16)gelu_erf(v);
                }
                *(uint2*)&out[rowbase + obase] = *(const uint2*)pk;
            }
        }
}

// ---------------------------------------------------------------------------
// global max of (y1 + x0gelu) over spatial, two stages
// ---------------------------------------------------------------------------
__global__ __launch_bounds__(256) void maxpart_kernel(
    const __bf16* __restrict__ y1, const __bf16* __restrict__ xt0,
    float* __restrict__ part)
{
    const int o = threadIdx.x;
    const int chunk = blockIdx.x & 63;
    const int b = blockIdx.x >> 6;
    float mx = -1e30f;
    for (int pp = 0; pp < 64; ++pp) {
        int p = chunk * 64 + pp;
        float a = (float)y1[((size_t)(b * 4096 + p)) * 256 + o];
        float c = (float)xt0[((size_t)(b * 4096 + p)) * 512 + o];
        mx = fmaxf(mx, a + c);
    }
    part[((size_t)(b * 64 + chunk)) * 256 + o] = mx;
}

__global__ __launch_bounds__(256) void maxfin_kernel(
    const float* __restrict__ part, float* __restrict__ out)
{
    const int o = threadIdx.x;
    const int b = blockIdx.x;
    float mx = -1e30f;
    for (int c = 0; c < 64; ++c)
        mx = fmaxf(mx, part[((size_t)(b * 64 + c)) * 256 + o]);
    out[b * 256 + o] = mx;
}

// ---------------------------------------------------------------------------
extern "C" void kernel_launch(void* const* d_in, const int* in_sizes, int n_in,
                              void* d_out, int out_size, void* d_ws, size_t ws_size,
                              hipStream_t stream)
{
    const float* in0  = (const float*)d_in[0];
    const float* in1  = (const float*)d_in[1];
    const float* w_q  = (const float*)d_in[2];
    const float* b_q  = (const float*)d_in[3];
    const float* w_k  = (const float*)d_in[4];
    const float* b_k  = (const float*)d_in[5];
    const float* w_v  = (const float*)d_in[6];
    const float* b_v  = (const float*)d_in[7];
    const float* w_o  = (const float*)d_in[8];
    const float* b_o  = (const float*)d_in[9];
    const float* bn0g = (const float*)d_in[10];
    const float* bn0b = (const float*)d_in[11];
    const float* bn0m = (const float*)d_in[12];
    const float* bn0v = (const float*)d_in[13];
    const float* cbw0 = (const float*)d_in[14];
    const float* cbb0 = (const float*)d_in[15];
    const float* cb0g = (const float*)d_in[16];
    const float* cb0b = (const float*)d_in[17];
    const float* cb0m = (const float*)d_in[18];
    const float* cb0v = (const float*)d_in[19];
    const float* cbw1 = (const float*)d_in[20];
    const float* cbb1 = (const float*)d_in[21];
    const float* cb1g = (const float*)d_in[22];
    const float* cb1b = (const float*)d_in[23];
    const float* cb1m = (const float*)d_in[24];
    const float* cb1v = (const float*)d_in[25];

    char* wsb = (char*)d_ws;
    const size_t MB = 1u << 20;
    __bf16* Xt0  = (__bf16*)(wsb);
    __bf16* Xin1 = (__bf16*)(wsb + 16 * MB);
    __bf16* Opart= (__bf16*)(wsb + 16 * MB);
    __bf16* Qswz = (__bf16*)(wsb + 24 * MB);
    __bf16* x0   = (__bf16*)(wsb + 24 * MB);
    __bf16* Kswz = (__bf16*)(wsb + 28 * MB);
    __bf16* y0   = (__bf16*)(wsb + 24 * MB);
    __bf16* Vswz = (__bf16*)(wsb + 32 * MB);
    __bf16* y1   = (__bf16*)(wsb + 32 * MB);
    __bf16* wqb  = (__bf16*)(wsb + 40 * MB);
    __bf16* wkb  = (__bf16*)(wsb + 40 * MB + 65536);
    __bf16* wvb  = (__bf16*)(wsb + 40 * MB + 2 * 65536);
    __bf16* wob  = (__bf16*)(wsb + 40 * MB + 3 * 65536);
    __bf16* Wt0  = (__bf16*)(wsb + 40 * MB + 4 * 65536);              // 2359296 B
    __bf16* Wt1  = (__bf16*)(wsb + 40 * MB + 4 * 65536 + 2359296);    // 1179648 B
    float*  Mpart= (float*)(wsb + 44 * MB);                            // 128KB
    float*  Lpart= (float*)(wsb + 44 * MB + 131072);                   // 128KB
    float*  part = (float*)(wsb + 44 * MB + 2 * 131072);               // 256KB
    float* outp = (float*)d_out;

    nhwc_cast_kernel<<<dim3(64, 4, 4), 256, 0, stream>>>(in0, Xt0, 256, 512);
    nhwc_cast_kernel<<<dim3(64, 4, 4), 256, 0, stream>>>(in1, Xin1, 0, 256);
    wtrans_kernel<<<1280, 256, 0, stream>>>(cbw0, cbw1, w_q, w_k, w_v, w_o,
                                            Wt0, Wt1, wqb, wkb, wvb, wob);
    proj_mfma_kernel<<<dim3(32, 1, 12), 256, 0, stream>>>(
        Xt0, Xin1, wqb, wkb, wvb, b_q, b_k, b_v, Vswz, Kswz, Qswz);
    attn_mfma_kernel<<<1024, 256, 0, stream>>>(Qswz, Kswz, Vswz, Opart, Mpart, Lpart);
    attn_merge_kernel<<<256, 256, 0, stream>>>(Opart, Mpart, Lpart, x0);
    convo_mfma_kernel<<<dim3(32, 2, 4), 256, 0, stream>>>(
        x0, wob, b_o, bn0g, bn0b, bn0m, bn0v, Xt0);
    conv3x3_mfma_kernel<512><<<256, 256, 0, stream>>>(Xt0, Wt0, cbb0, cb0g, cb0b, cb0m, cb0v, y0);
    conv3x3_mfma_kernel<256><<<256, 256, 0, stream>>>(y0, Wt1, cbb1, cb1g, cb1b, cb1m, cb1v, y1);
    maxpart_kernel<<<256, 256, 0, stream>>>(y1, Xt0, part);
    maxfin_kernel<<<4, 256, 0, stream>>>(part, outp);
}

// Round 9
// 294.358 us; speedup vs baseline: 1.2712x; 1.0396x over previous
//
#include <hip/hip_runtime.h>
#include <math.h>

#define B_ 4
#define C_ 256
#define CH_ 128
#define NN 4096   // H*W = 64*64

typedef __bf16 bf16x8 __attribute__((ext_vector_type(8)));
typedef float f32x16 __attribute__((ext_vector_type(16)));
typedef unsigned int u32;

__device__ __forceinline__ float gelu_erf(float x) {
    return 0.5f * x * (1.0f + erff(x * 0.7071067811865476f));
}

__device__ __forceinline__ u32 pkbf(float a, float b) {
    union { __bf16 h[2]; u32 u; } x;
    x.h[0] = (__bf16)a; x.h[1] = (__bf16)b;
    return x.u;
}

// ---------------------------------------------------------------------------
// NCHW fp32 -> NHWC bf16 cast/transpose.
// ---------------------------------------------------------------------------
__global__ __launch_bounds__(256) void nhwc_cast_kernel(
    const float* __restrict__ src, __bf16* __restrict__ dst,
    int colbase, int rowstride)
{
    __shared__ float Lt[64][65];
    const int t = threadIdx.x;
    const int p0 = blockIdx.x * 64;
    const int c0 = blockIdx.y * 64;
    const int b  = blockIdx.z;
#pragma unroll
    for (int i = 0; i < 16; ++i) {
        int idx = t + i * 256;
        int c = idx >> 6, p = idx & 63;
        Lt[c][p] = src[((size_t)(b * 256 + c0 + c)) * 4096 + p0 + p];
    }
    __syncthreads();
#pragma unroll
    for (int i = 0; i < 16; ++i) {
        int idx = t + i * 256;
        int p = idx >> 6, c = idx & 63;
        dst[((size_t)(b * 4096 + p0 + p)) * rowstride + colbase + c0 + c] = (__bf16)Lt[c][p];
    }
}

// ---------------------------------------------------------------------------
// Weight transform.
// conv3x3 weights -> FRAGMENT-MAJOR bf16: Wfrag[chunk][k9][f][lane64][8]
//   element (o, ci, k): chunk=ci>>4, f=o>>5, lane=(o&31)+32*((ci>>3)&1), j=ci&7
// 1x1 weights -> plain bf16 copy.
// ---------------------------------------------------------------------------
__global__ __launch_bounds__(256) void wtrans_kernel(
    const float* __restrict__ w0, const float* __restrict__ w1,
    const float* __restrict__ wq, const float* __restrict__ wk,
    const float* __restrict__ wv, const float* __restrict__ wo,
    __bf16* __restrict__ Wt0, __bf16* __restrict__ Wt1,
    __bf16* __restrict__ wqb, __bf16* __restrict__ wkb,
    __bf16* __restrict__ wvb, __bf16* __restrict__ wob)
{
    int id = blockIdx.x * 256 + threadIdx.x;
    if (id < 131072) {
        int o = id >> 9, ci = id & 511;
        const float* s = w0 + (size_t)id * 9;
        const int chunk = ci >> 4, f = o >> 5;
        const int lane = (o & 31) + 32 * ((ci >> 3) & 1);
        const int j = ci & 7;
#pragma unroll
        for (int k = 0; k < 9; ++k)
            Wt0[((size_t)(chunk * 9 + k) * 8 + f) * 512 + lane * 8 + j] = (__bf16)s[k];
    } else if (id < 196608) {
        int id2 = id - 131072;
        int o = id2 >> 8, ci = id2 & 255;
        const float* s = w1 + (size_t)id2 * 9;
        const int chunk = ci >> 4, f = o >> 5;
        const int lane = (o & 31) + 32 * ((ci >> 3) & 1);
        const int j = ci & 7;
#pragma unroll
        for (int k = 0; k < 9; ++k)
            Wt1[((size_t)(chunk * 9 + k) * 8 + f) * 512 + lane * 8 + j] = (__bf16)s[k];
    } else {
        int id3 = id - 196608;     // 0..131071
        int sel = id3 >> 15;
        int k = id3 & 32767;
        const float* s = sel == 0 ? wq : sel == 1 ? wk : sel == 2 ? wv : wo;
        __bf16* d = sel == 0 ? wqb : sel == 1 ? wkb : sel == 2 ? wvb : wob;
        d[k] = (__bf16)s[k];
    }
}

// ---------------------------------------------------------------------------
// 1x1 projections via MFMA, outputs in MFMA-fragment-major order (unchanged).
// ---------------------------------------------------------------------------
__global__ __launch_bounds__(256) void proj_mfma_kernel(
    const __bf16* __restrict__ Xt0,   // [4][4096][512], in0 at cols 256-511
    const __bf16* __restrict__ Xin1,  // [4][4096][256]
    const __bf16* __restrict__ wqb, const __bf16* __restrict__ wkb,
    const __bf16* __restrict__ wvb,
    const float* __restrict__ bq, const float* __restrict__ bk,
    const float* __restrict__ bv,
    __bf16* __restrict__ Vswz, __bf16* __restrict__ Kswz, __bf16* __restrict__ Qswz)
{
    __shared__ __align__(16) __bf16 Vt[4][64][80];
    __shared__ float biasl[128];

    const int t = threadIdx.x;
    const int which = blockIdx.z % 3;
    const int b = blockIdx.z / 3;
    const int p0 = blockIdx.x * 128;

    const __bf16* W = which == 0 ? wqb : which == 1 ? wkb : wvb;
    const float* bias = which == 0 ? bq : which == 1 ? bk : bv;
    const __bf16* src; int stride, colb;
    if (which == 2) { src = Xin1 + (size_t)b * NN * 256; stride = 256; colb = 0; }
    else            { src = Xt0  + (size_t)b * NN * 512; stride = 512; colb = 256; }

    if (t < 128) biasl[t] = bias[t];
    __syncthreads();

    const int lane = t & 63, w = t >> 6;
    const int l31 = lane & 31, hi = lane >> 5;
    const int wo2 = w >> 1, wp2 = w & 1;
    const int ob = wo2 * 64;
    const int pb = p0 + wp2 * 64;

    f32x16 acc[2][2];
#pragma unroll
    for (int i = 0; i < 2; ++i)
#pragma unroll
        for (int j = 0; j < 2; ++j)
#pragma unroll
            for (int e = 0; e < 16; ++e) acc[i][j][e] = 0.f;

#pragma unroll
    for (int kc = 0; kc < 16; ++kc) {
        bf16x8 a0 = *(const bf16x8*)&W[(size_t)(ob + l31) * 256 + hi * 8 + kc * 16];
        bf16x8 a1 = *(const bf16x8*)&W[(size_t)(ob + 32 + l31) * 256 + hi * 8 + kc * 16];
        bf16x8 b0 = *(const bf16x8*)&src[(size_t)(pb + l31) * stride + colb + hi * 8 + kc * 16];
        bf16x8 b1 = *(const bf16x8*)&src[(size_t)(pb + 32 + l31) * stride + colb + hi * 8 + kc * 16];
        acc[0][0] = __builtin_amdgcn_mfma_f32_32x32x16_bf16(a0, b0, acc[0][0], 0, 0, 0);
        acc[0][1] = __builtin_amdgcn_mfma_f32_32x32x16_bf16(a0, b1, acc[0][1], 0, 0, 0);
        acc[1][0] = __builtin_amdgcn_mfma_f32_32x32x16_bf16(a1, b0, acc[1][0], 0, 0, 0);
        acc[1][1] = __builtin_amdgcn_mfma_f32_32x32x16_bf16(a1, b1, acc[1][1], 0, 0, 0);
    }

    if (which) {
        __bf16* dst = (which == 1 ? Kswz : Qswz) + (size_t)b * NN * CH_;
#pragma unroll
        for (int mi = 0; mi < 2; ++mi)
#pragma unroll
            for (int nx = 0; nx < 2; ++nx) {
                const int tile = (pb >> 5) + nx;
#pragma unroll
                for (int q4 = 0; q4 < 4; ++q4) {
                    const int ic = (ob >> 4) + mi * 2 + (q4 >> 1);
                    const int og = ob + mi * 32 + q4 * 8 + hi * 4;
                    __bf16 pk[4];
#pragma unroll
                    for (int j = 0; j < 4; ++j)
                        pk[j] = (__bf16)(acc[mi][nx][q4 * 4 + j] + biasl[og + j]);
                    const size_t el = ((size_t)(tile * 8 + ic) * 64
                                       + l31 + 32 * (q4 & 1)) * 8 + hi * 4;
                    *(uint2*)&dst[el] = *(const uint2*)pk;
                }
            }
    } else {
#pragma unroll
        for (int mi = 0; mi < 2; ++mi)
#pragma unroll
            for (int nx = 0; nx < 2; ++nx) {
                const int ploc = nx * 32 + l31;
#pragma unroll
                for (int q4 = 0; q4 < 4; ++q4) {
                    const int oloc = mi * 32 + q4 * 8 + hi * 4;
#pragma unroll
                    for (int j = 0; j < 4; ++j)
                        Vt[w][oloc + j][ploc] =
                            (__bf16)(acc[mi][nx][q4 * 4 + j] + biasl[ob + oloc + j]);
                }
            }
        __syncthreads();
        __bf16* dst = Vswz + (size_t)b * NN * CH_;
#pragma unroll
        for (int s = 0; s < 8; ++s) {
            const int tl = s >> 2, jc = (s >> 1) & 1, il = s & 1;
            const int tile_g = (pb >> 5) + tl;
            const int icf_g = (ob >> 5) + il;
            const int i_loc = il * 32 + l31;
            const int kk = tl * 32 + jc * 16 + hi * 8;
            uint4 v = *(const uint4*)&Vt[w][i_loc][kk];
            const size_t el = ((size_t)((tile_g * 2 + jc) * 4 + icf_g) * 64 + lane) * 8;
            *(uint4*)&dst[el] = v;
        }
    }
}

// ---------------------------------------------------------------------------
// MFMA bf16 flash attention (unchanged from R8 — verified, ~35us).
// ---------------------------------------------------------------------------
__global__ __launch_bounds__(256, 4) void attn_mfma_kernel(
    const __bf16* __restrict__ Qswz, const __bf16* __restrict__ Kswz,
    const __bf16* __restrict__ Vswz,
    __bf16* __restrict__ Opart, float* __restrict__ Mpart, float* __restrict__ Lpart)
{
    __shared__ __bf16 Op[4][128][34];
    __shared__ float Ml[4][32], Ll[4][32];

    const int t = threadIdx.x;
    const int lane = t & 63;
    const int w = t >> 6;
    const int l31 = lane & 31;
    const int hi = lane >> 5;

    const int bid = blockIdx.x;
    const int xcd = bid & 7;
    const int b = xcd >> 1;
    const int local = bid >> 3;
    const int qt = (xcd & 1) * 64 + (local & 63);
    const int half = local >> 6;
    const int q0 = qt * 32;

    const __bf16* Qs = Qswz + (size_t)b * NN * CH_ + (size_t)qt * 4096 + lane * 8;
    bf16x8 qf[8];
#pragma unroll
    for (int ic = 0; ic < 8; ++ic) qf[ic] = *(const bf16x8*)(Qs + ic * 512);

    const __bf16* Ks = Kswz + (size_t)b * NN * CH_ + lane * 8;
    const __bf16* Vs = Vswz + (size_t)b * NN * CH_ + lane * 8;

    f32x16 oacc[4];
#pragma unroll
    for (int i = 0; i < 4; ++i)
#pragma unroll
        for (int e = 0; e < 16; ++e) oacc[i][e] = 0.f;

    float m = -3e38f, lsum = 0.f;
    const int tbase = half * 64 + w * 16;

    for (int jt = 0; jt < 16; ++jt) {
        const int tile = tbase + jt;
        f32x16 s;
#pragma unroll
        for (int e = 0; e < 16; ++e) s[e] = 0.f;
        const __bf16* Kt = Ks + (size_t)tile * 4096;
#pragma unroll
        for (int ic = 0; ic < 8; ++ic) {
            bf16x8 kf = *(const bf16x8*)(Kt + ic * 512);
            s = __builtin_amdgcn_mfma_f32_32x32x16_bf16(kf, qf[ic], s, 0, 0, 0);
        }
        float t8[8];
#pragma unroll
        for (int e = 0; e < 8; ++e) t8[e] = fmaxf(s[e], s[e + 8]);
#pragma unroll
        for (int e = 0; e < 4; ++e) t8[e] = fmaxf(t8[e], t8[e + 4]);
        t8[0] = fmaxf(t8[0], t8[2]); t8[1] = fmaxf(t8[1], t8[3]);
        float mu = fmaxf(t8[0], t8[1]);
        const float pm = fmaxf(mu, __shfl_xor(mu, 32));
        if (!__all(pm <= m + 8.f)) {
            const float mn = fmaxf(m, pm);
            const float al = __expf(m - mn);
            m = mn;
            lsum *= al;
#pragma unroll
            for (int i = 0; i < 4; ++i)
#pragma unroll
                for (int e = 0; e < 16; ++e) oacc[i][e] *= al;
        }
#pragma unroll
        for (int e = 0; e < 16; ++e) s[e] = __expf(s[e] - m);
        float s8[8];
#pragma unroll
        for (int e = 0; e < 8; ++e) s8[e] = s[e] + s[e + 8];
#pragma unroll
        for (int e = 0; e < 4; ++e) s8[e] += s8[e + 4];
        s8[0] += s8[2]; s8[1] += s8[3];
        float su = s8[0] + s8[1];
        lsum += su + __shfl_xor(su, 32);

        const __bf16* Vt = Vs + (size_t)tile * 4096;
        {
            u32 w0 = pkbf(s[0], s[1]), w1 = pkbf(s[2], s[3]);
            u32 w2 = pkbf(s[4], s[5]), w3 = pkbf(s[6], s[7]);
            asm("v_permlane32_swap_b32 %0, %1" : "+v"(w0), "+v"(w2));
            asm("v_permlane32_swap_b32 %0, %1" : "+v"(w1), "+v"(w3));
            union { u32 u4[4]; bf16x8 v; } pB;
            pB.u4[0] = w0; pB.u4[1] = w1; pB.u4[2] = w2; pB.u4[3] = w3;
#pragma unroll
            for (int icf = 0; icf < 4; ++icf) {
                bf16x8 vf = *(const bf16x8*)(Vt + icf * 512);
                oacc[icf] = __builtin_amdgcn_mfma_f32_32x32x16_bf16(vf, pB.v, oacc[icf], 0, 0, 0);
            }
        }
        {
            u32 w0 = pkbf(s[8], s[9]), w1 = pkbf(s[10], s[11]);
            u32 w2 = pkbf(s[12], s[13]), w3 = pkbf(s[14], s[15]);
            asm("v_permlane32_swap_b32 %0, %1" : "+v"(w0), "+v"(w2));
            asm("v_permlane32_swap_b32 %0, %1" : "+v"(w1), "+v"(w3));
            union { u32 u4[4]; bf16x8 v; } pB;
            pB.u4[0] = w0; pB.u4[1] = w1; pB.u4[2] = w2; pB.u4[3] = w3;
#pragma unroll
            for (int icf = 0; icf < 4; ++icf) {
                bf16x8 vf = *(const bf16x8*)(Vt + 2048 + icf * 512);
                oacc[icf] = __builtin_amdgcn_mfma_f32_32x32x16_bf16(vf, pB.v, oacc[icf], 0, 0, 0);
            }
        }
    }

#pragma unroll
    for (int icf = 0; icf < 4; ++icf)
#pragma unroll
        for (int q = 0; q < 16; ++q) {
            const int row = icf * 32 + (q & 3) + 8 * (q >> 2) + 4 * hi;
            Op[w][row][l31] = (__bf16)oacc[icf][q];
        }
    if (hi == 0) { Ml[w][l31] = m; Ll[w][l31] = lsum; }
    __syncthreads();
    {
        const int q = t & 31;
        const int i0g = (t >> 5) * 16;
        const float m0 = Ml[0][q], m1 = Ml[1][q], m2 = Ml[2][q], m3 = Ml[3][q];
        const float ms = fmaxf(fmaxf(m0, m1), fmaxf(m2, m3));
        const float a0 = __expf(m0 - ms), a1 = __expf(m1 - ms);
        const float a2 = __expf(m2 - ms), a3 = __expf(m3 - ms);
        const float den = a0 * Ll[0][q] + a1 * Ll[1][q] + a2 * Ll[2][q] + a3 * Ll[3][q];
        union { __bf16 h[16]; uint4 u4[2]; } pk;
#pragma unroll
        for (int ii = 0; ii < 16; ++ii) {
            const int i = i0g + ii;
            pk.h[ii] = (__bf16)(a0 * (float)Op[0][i][q] + a1 * (float)Op[1][i][q]
                              + a2 * (float)Op[2][i][q] + a3 * (float)Op[3][i][q]);
        }
        const size_t base = ((size_t)((half * 4 + b) * NN) + q0 + q) * CH_ + i0g;
        *(uint4*)&Opart[base] = pk.u4[0];
        *(uint4*)&Opart[base + 8] = pk.u4[1];
        if (t < 32) {
            Mpart[(size_t)(half * 4 + b) * NN + q0 + q] = ms;
            Lpart[(size_t)(half * 4 + b) * NN + q0 + q] = den;
        }
    }
}

// ---------------------------------------------------------------------------
// Merge the 2 KV-half partials -> x0 bf16 pos-major [4][4096][128]
// ---------------------------------------------------------------------------
__global__ __launch_bounds__(256) void attn_merge_kernel(
    const __bf16* __restrict__ Opart, const float* __restrict__ Mpart,
    const float* __restrict__ Lpart, __bf16* __restrict__ x0)
{
    const int id = blockIdx.x * 256 + threadIdx.x;
    const int qg = id >> 2;
    const int i0 = (id & 3) * 32;
    const int b = qg >> 12, q = qg & 4095;
    const size_t idx0 = (size_t)b * NN + q;
    const size_t idx1 = (size_t)(4 + b) * NN + q;
    const float m0 = Mpart[idx0], m1 = Mpart[idx1];
    const float ms = fmaxf(m0, m1);
    const float a0 = __expf(m0 - ms), a1 = __expf(m1 - ms);
    const float inv = 1.f / (a0 * Lpart[idx0] + a1 * Lpart[idx1]);
    const __bf16* O0 = &Opart[idx0 * CH_ + i0];
    const __bf16* O1 = &Opart[idx1 * CH_ + i0];
    union { __bf16 h[32]; uint4 u4[4]; } ov;
#pragma unroll
    for (int ii = 0; ii < 32; ++ii)
        ov.h[ii] = (__bf16)((a0 * (float)O0[ii] + a1 * (float)O1[ii]) * inv);
    uint4* dst = (uint4*)&x0[((size_t)b * NN + q) * CH_ + i0];
#pragma unroll
    for (int s = 0; s < 4; ++s) dst[s] = ov.u4[s];
}

// ---------------------------------------------------------------------------
// conv_o (1x1, 128->256) via MFMA + BN + GELU -> Xt0 cols 0-255 (unchanged)
// ---------------------------------------------------------------------------
__global__ __launch_bounds__(256) void convo_mfma_kernel(
    const __bf16* __restrict__ x0, const __bf16* __restrict__ wob,
    const float* __restrict__ bo,
    const float* __restrict__ g, const float* __restrict__ bb,
    const float* __restrict__ mm, const float* __restrict__ vv,
    __bf16* __restrict__ Xt0)
{
    __shared__ float scb[128], shb[128], bsb[128];
    const int t = threadIdx.x;
    const int p0 = blockIdx.x * 128;
    const int o0 = blockIdx.y * 128;
    const int b = blockIdx.z;
    if (t < 128) {
        const int o = o0 + t;
        const float sc = g[o] * rsqrtf(vv[o] + 1e-5f);
        scb[t] = sc; shb[t] = bb[o] - mm[o] * sc; bsb[t] = bo[o];
    }
    __syncthreads();

    const int lane = t & 63, w = t >> 6;
    const int l31 = lane & 31, hi = lane >> 5;
    const int wo2 = w >> 1, wp2 = w & 1;
    const int ob = o0 + wo2 * 64;
    const int pb = p0 + wp2 * 64;

    f32x16 acc[2][2];
#pragma unroll
    for (int i = 0; i < 2; ++i)
#pragma unroll
        for (int j = 0; j < 2; ++j)
#pragma unroll
            for (int e = 0; e < 16; ++e) acc[i][j][e] = 0.f;

#pragma unroll
    for (int kc = 0; kc < 8; ++kc) {
        bf16x8 a0 = *(const bf16x8*)&wob[(size_t)(ob + l31) * 128 + hi * 8 + kc * 16];
        bf16x8 a1 = *(const bf16x8*)&wob[(size_t)(ob + 32 + l31) * 128 + hi * 8 + kc * 16];
        bf16x8 b0 = *(const bf16x8*)&x0[((size_t)(b * NN) + pb + l31) * 128 + hi * 8 + kc * 16];
        bf16x8 b1 = *(const bf16x8*)&x0[((size_t)(b * NN) + pb + 32 + l31) * 128 + hi * 8 + kc * 16];
        acc[0][0] = __builtin_amdgcn_mfma_f32_32x32x16_bf16(a0, b0, acc[0][0], 0, 0, 0);
        acc[0][1] = __builtin_amdgcn_mfma_f32_32x32x16_bf16(a0, b1, acc[0][1], 0, 0, 0);
        acc[1][0] = __builtin_amdgcn_mfma_f32_32x32x16_bf16(a1, b0, acc[1][0], 0, 0, 0);
        acc[1][1] = __builtin_amdgcn_mfma_f32_32x32x16_bf16(a1, b1, acc[1][1], 0, 0, 0);
    }

#pragma unroll
    for (int mi = 0; mi < 2; ++mi)
#pragma unroll
        for (int nx = 0; nx < 2; ++nx) {
            const int p = pb + nx * 32 + l31;
            const size_t rowbase = ((size_t)(b * NN) + p) * 512 + o0;
#pragma unroll
            for (int q4 = 0; q4 < 4; ++q4) {
                const int ol = wo2 * 64 + mi * 32 + q4 * 8 + hi * 4;
                __bf16 pk[4];
#pragma unroll
                for (int j = 0; j < 4; ++j) {
                    float v = acc[mi][nx][q4 * 4 + j] + bsb[ol + j];
                    v = v * scb[ol + j] + shb[ol + j];
                    pk[j] = (__bf16)gelu_erf(v);
                }
                *(uint2*)&Xt0[rowbase + ol] = *(const uint2*)pk;
            }
        }
}

// ---------------------------------------------------------------------------
// 3x3 conv via MFMA. Weights read DIRECTLY from global in fragment-major
// order (coalesced lane*16B, L2-resident) — halves LDS traffic vs R8.
// Block: 64 o x 128 pos (2 image rows), 4 waves each 64o x 32pos.
// LDS: input-tile double buffer only (2 x 8448B). grid 512 -> 2 blocks/CU.
// ---------------------------------------------------------------------------
template<int IC>
__global__ __launch_bounds__(256) void conv3x3_mfma_kernel(
    const __bf16* __restrict__ Xsrc,   // NHWC [4][4096][IC]
    const __bf16* __restrict__ Wf,     // frag-major [NC][9][8][64][8]
    const float* __restrict__ bias, const float* __restrict__ bng,
    const float* __restrict__ bnb, const float* __restrict__ bnm,
    const float* __restrict__ bnv,
    __bf16* __restrict__ out)          // NHWC [4][4096][256]
{
    constexpr int NC = IC / 16;
    __shared__ __align__(16) char Tl[2][8448];   // [4 rows][66 xh][16 ci] bf16
    __shared__ float scb[64], shb[64], bsb[64];

    const int t = threadIdx.x;
    const int bid = blockIdx.x;
    const int xcd = bid & 7, local = bid >> 3;        // 512 blocks
    const int combo = xcd * 2 + (local >> 5);         // 0..15, pinned per XCD
    const int pt = local & 31;
    const int m = combo & 3, b = combo >> 2;
    const int o0 = m * 64;
    const int y0 = pt * 2;

    if (t < 64) {
        const int o = o0 + t;
        const float sc = bng[o] * rsqrtf(bnv[o] + 1e-5f);
        scb[t] = sc; shb[t] = bnb[o] - bnm[o] * sc; bsb[t] = bias[o];
    }

    const int lane = t & 63, w = t >> 6;
    const int l31 = lane & 31, hi = lane >> 5;
    const int rowl = w >> 1;          // wave's output row (0,1)
    const int xh2 = w & 1;            // wave's 32-px half

    uint4 ireg[2];

    auto loadI = [&](int c0) {
#pragma unroll
        for (int s = 0; s < 2; ++s) {
            int u = t + s * 256;
            int g = u & 1, x = (u >> 1) & 63, r = u >> 7;   // r 0..3
            int yy = y0 - 1 + r;
            if (yy >= 0 && yy < 64)
                ireg[s] = *(const uint4*)&Xsrc[((size_t)(b * 4096 + yy * 64 + x)) * IC + c0 + g * 8];
            else
                ireg[s] = make_uint4(0u, 0u, 0u, 0u);
        }
    };
    auto writeI = [&](char* dst) {
#pragma unroll
        for (int s = 0; s < 2; ++s) {
            int u = t + s * 256;
            int g = u & 1, x = (u >> 1) & 63, r = u >> 7;
            int xh = x + 1;
            int byte = r * 2112 + ((xh * 32 + g * 16) ^ ((xh & 7) << 4));
            *(uint4*)(dst + byte) = ireg[s];
        }
        if (t < 16) {   // x halo zeros (xh=0 and 65) for 4 rows x 2 ci-halves
            int g = t & 1, side = (t >> 1) & 1, r = t >> 2;
            int xh = side ? 65 : 0;
            int byte = r * 2112 + ((xh * 32 + g * 16) ^ ((xh & 7) << 4));
            *(uint4*)(dst + byte) = make_uint4(0u, 0u, 0u, 0u);
        }
    };

    f32x16 acc[2];
#pragma unroll
    for (int i = 0; i < 2; ++i)
#pragma unroll
        for (int e = 0; e < 16; ++e) acc[i][e] = 0.f;

    // per-lane B-read base offsets for the 3 dx values (wave-uniform row added later)
    int Boff[3];
#pragma unroll
    for (int dx = 0; dx < 3; ++dx) {
        int xh = xh2 * 32 + l31 + dx;
        Boff[dx] = (xh * 32 + hi * 16) ^ ((xh & 7) << 4);
    }
    // weight fragment base: f0 = m*2 (+mi)
    const __bf16* Wb = Wf + ((size_t)(m * 2) * 64 + lane) * 8;

    auto compute = [&](int c, const char* Tb) {
#pragma unroll
        for (int k9 = 0; k9 < 9; ++k9) {
            const int dy = k9 / 3, dx = k9 % 3;
            const __bf16* wp = Wb + (size_t)(c * 9 + k9) * 4096;
            bf16x8 a0 = *(const bf16x8*)(wp);
            bf16x8 a1 = *(const bf16x8*)(wp + 512);
            const char* Trow = Tb + (rowl + dy) * 2112;
            bf16x8 bv = *(const bf16x8*)(Trow + Boff[dx]);
            acc[0] = __builtin_amdgcn_mfma_f32_32x32x16_bf16(a0, bv, acc[0], 0, 0, 0);
            acc[1] = __builtin_amdgcn_mfma_f32_32x32x16_bf16(a1, bv, acc[1], 0, 0, 0);
        }
    };

    loadI(0);
    writeI(Tl[0]);
    __syncthreads();
    for (int c = 0; c < NC; ++c) {
        const int cur = c & 1;
        if (c + 1 < NC) loadI((c + 1) * 16);
        compute(c, Tl[cur]);
        __syncthreads();
        if (c + 1 < NC) writeI(Tl[cur ^ 1]);
        __syncthreads();
    }

    // epilogue: bias + BN + GELU, store NHWC bf16
    {
        const int p = (y0 + rowl) * 64 + xh2 * 32 + l31;
        const size_t rowbase = ((size_t)(b * 4096 + p)) * 256 + o0;
#pragma unroll
        for (int mi = 0; mi < 2; ++mi)
#pragma unroll
            for (int q = 0; q < 4; ++q) {
                const int obase = mi * 32 + q * 8 + hi * 4;
                __bf16 pk[4];
#pragma unroll
                for (int j = 0; j < 4; ++j) {
                    float v = acc[mi][q * 4 + j] + bsb[obase + j];
                    v = v * scb[obase + j] + shb[obase + j];
                    pk[j] = (__bf16)gelu_erf(v);
                }
                *(uint2*)&out[rowbase + obase] = *(const uint2*)pk;
            }
    }
}

// ---------------------------------------------------------------------------
// global max of (y1 + x0gelu) over spatial, two stages
// ---------------------------------------------------------------------------
__global__ __launch_bounds__(256) void maxpart_kernel(
    const __bf16* __restrict__ y1, const __bf16* __restrict__ xt0,
    float* __restrict__ part)
{
    const int o = threadIdx.x;
    const int chunk = blockIdx.x & 63;
    const int b = blockIdx.x >> 6;
    float mx = -1e30f;
    for (int pp = 0; pp < 64; ++pp) {
        int p = chunk * 64 + pp;
        float a = (float)y1[((size_t)(b * 4096 + p)) * 256 + o];
        float c = (float)xt0[((size_t)(b * 4096 + p)) * 512 + o];
        mx = fmaxf(mx, a + c);
    }
    part[((size_t)(b * 64 + chunk)) * 256 + o] = mx;
}

__global__ __launch_bounds__(256) void maxfin_kernel(
    const float* __restrict__ part, float* __restrict__ out)
{
    const int o = threadIdx.x;
    const int b = blockIdx.x;
    float mx = -1e30f;
    for (int c = 0; c < 64; ++c)
        mx = fmaxf(mx, part[((size_t)(b * 64 + c)) * 256 + o]);
    out[b * 256 + o] = mx;
}

// ---------------------------------------------------------------------------
extern "C" void kernel_launch(void* const* d_in, const int* in_sizes, int n_in,
                              void* d_out, int out_size, void* d_ws, size_t ws_size,
                              hipStream_t stream)
{
    const float* in0  = (const float*)d_in[0];
    const float* in1  = (const float*)d_in[1];
    const float* w_q  = (const float*)d_in[2];
    const float* b_q  = (const float*)d_in[3];
    const float* w_k  = (const float*)d_in[4];
    const float* b_k  = (const float*)d_in[5];
    const float* w_v  = (const float*)d_in[6];
    const float* b_v  = (const float*)d_in[7];
    const float* w_o  = (const float*)d_in[8];
    const float* b_o  = (const float*)d_in[9];
    const float* bn0g = (const float*)d_in[10];
    const float* bn0b = (const float*)d_in[11];
    const float* bn0m = (const float*)d_in[12];
    const float* bn0v = (const float*)d_in[13];
    const float* cbw0 = (const float*)d_in[14];
    const float* cbb0 = (const float*)d_in[15];
    const float* cb0g = (const float*)d_in[16];
    const float* cb0b = (const float*)d_in[17];
    const float* cb0m = (const float*)d_in[18];
    const float* cb0v = (const float*)d_in[19];
    const float* cbw1 = (const float*)d_in[20];
    const float* cbb1 = (const float*)d_in[21];
    const float* cb1g = (const float*)d_in[22];
    const float* cb1b = (const float*)d_in[23];
    const float* cb1m = (const float*)d_in[24];
    const float* cb1v = (const float*)d_in[25];

    char* wsb = (char*)d_ws;
    const size_t MB = 1u << 20;
    __bf16* Xt0  = (__bf16*)(wsb);
    __bf16* Xin1 = (__bf16*)(wsb + 16 * MB);
    __bf16* Opart= (__bf16*)(wsb + 16 * MB);
    __bf16* Qswz = (__bf16*)(wsb + 24 * MB);
    __bf16* x0   = (__bf16*)(wsb + 24 * MB);
    __bf16* Kswz = (__bf16*)(wsb + 28 * MB);
    __bf16* y0   = (__bf16*)(wsb + 24 * MB);
    __bf16* Vswz = (__bf16*)(wsb + 32 * MB);
    __bf16* y1   = (__bf16*)(wsb + 32 * MB);
    __bf16* wqb  = (__bf16*)(wsb + 40 * MB);
    __bf16* wkb  = (__bf16*)(wsb + 40 * MB + 65536);
    __bf16* wvb  = (__bf16*)(wsb + 40 * MB + 2 * 65536);
    __bf16* wob  = (__bf16*)(wsb + 40 * MB + 3 * 65536);
    __bf16* Wt0  = (__bf16*)(wsb + 40 * MB + 4 * 65536);              // 2359296 B
    __bf16* Wt1  = (__bf16*)(wsb + 40 * MB + 4 * 65536 + 2359296);    // 1179648 B
    float*  Mpart= (float*)(wsb + 44 * MB);
    float*  Lpart= (float*)(wsb + 44 * MB + 131072);
    float*  part = (float*)(wsb + 44 * MB + 2 * 131072);
    float* outp = (float*)d_out;

    nhwc_cast_kernel<<<dim3(64, 4, 4), 256, 0, stream>>>(in0, Xt0, 256, 512);
    nhwc_cast_kernel<<<dim3(64, 4, 4), 256, 0, stream>>>(in1, Xin1, 0, 256);
    wtrans_kernel<<<1280, 256, 0, stream>>>(cbw0, cbw1, w_q, w_k, w_v, w_o,
                                            Wt0, Wt1, wqb, wkb, wvb, wob);
    proj_mfma_kernel<<<dim3(32, 1, 12), 256, 0, stream>>>(
        Xt0, Xin1, wqb, wkb, wvb, b_q, b_k, b_v, Vswz, Kswz, Qswz);
    attn_mfma_kernel<<<1024, 256, 0, stream>>>(Qswz, Kswz, Vswz, Opart, Mpart, Lpart);
    attn_merge_kernel<<<256, 256, 0, stream>>>(Opart, Mpart, Lpart, x0);
    convo_mfma_kernel<<<dim3(32, 2, 4), 256, 0, stream>>>(
        x0, wob, b_o, bn0g, bn0b, bn0m, bn0v, Xt0);
    conv3x3_mfma_kernel<512><<<512, 256, 0, stream>>>(Xt0, Wt0, cbb0, cb0g, cb0b, cb0m, cb0v, y0);
    conv3x3_mfma_kernel<256><<<512, 256, 0, stream>>>(y0, Wt1, cbb1, cb1g, cb1b, cb1m, cb1v, y1);
    maxpart_kernel<<<256, 256, 0, stream>>>(y1, Xt0, part);
    maxfin_kernel<<<4, 256, 0, stream>>>(part, outp);
}

// Round 10
// 251.303 us; speedup vs baseline: 1.4890x; 1.1713x over previous
//
#include <hip/hip_runtime.h>
#include <math.h>

#define B_ 4
#define C_ 256
#define CH_ 128
#define NN 4096   // H*W = 64*64

typedef __bf16 bf16x8 __attribute__((ext_vector_type(8)));
typedef float f32x16 __attribute__((ext_vector_type(16)));
typedef unsigned int u32;

__device__ __forceinline__ float gelu_erf(float x) {
    return 0.5f * x * (1.0f + erff(x * 0.7071067811865476f));
}

__device__ __forceinline__ u32 pkbf(float a, float b) {
    union { __bf16 h[2]; u32 u; } x;
    x.h[0] = (__bf16)a; x.h[1] = (__bf16)b;
    return x.u;
}

// ---------------------------------------------------------------------------
// NCHW fp32 -> NHWC bf16 cast/transpose.
// ---------------------------------------------------------------------------
__global__ __launch_bounds__(256) void nhwc_cast_kernel(
    const float* __restrict__ src, __bf16* __restrict__ dst,
    int colbase, int rowstride)
{
    __shared__ float Lt[64][65];
    const int t = threadIdx.x;
    const int p0 = blockIdx.x * 64;
    const int c0 = blockIdx.y * 64;
    const int b  = blockIdx.z;
#pragma unroll
    for (int i = 0; i < 16; ++i) {
        int idx = t + i * 256;
        int c = idx >> 6, p = idx & 63;
        Lt[c][p] = src[((size_t)(b * 256 + c0 + c)) * 4096 + p0 + p];
    }
    __syncthreads();
#pragma unroll
    for (int i = 0; i < 16; ++i) {
        int idx = t + i * 256;
        int p = idx >> 6, c = idx & 63;
        dst[((size_t)(b * 4096 + p0 + p)) * rowstride + colbase + c0 + c] = (__bf16)Lt[c][p];
    }
}

// ---------------------------------------------------------------------------
// Weight transform.
// conv3x3 weights -> FRAGMENT-MAJOR bf16: Wfrag[chunk][k9][f][lane64][8]
// 1x1 weights -> plain bf16 copy.
// ---------------------------------------------------------------------------
__global__ __launch_bounds__(256) void wtrans_kernel(
    const float* __restrict__ w0, const float* __restrict__ w1,
    const float* __restrict__ wq, const float* __restrict__ wk,
    const float* __restrict__ wv, const float* __restrict__ wo,
    __bf16* __restrict__ Wt0, __bf16* __restrict__ Wt1,
    __bf16* __restrict__ wqb, __bf16* __restrict__ wkb,
    __bf16* __restrict__ wvb, __bf16* __restrict__ wob)
{
    int id = blockIdx.x * 256 + threadIdx.x;
    if (id < 131072) {
        int o = id >> 9, ci = id & 511;
        const float* s = w0 + (size_t)id * 9;
        const int chunk = ci >> 4, f = o >> 5;
        const int lane = (o & 31) + 32 * ((ci >> 3) & 1);
        const int j = ci & 7;
#pragma unroll
        for (int k = 0; k < 9; ++k)
            Wt0[((size_t)(chunk * 9 + k) * 8 + f) * 512 + lane * 8 + j] = (__bf16)s[k];
    } else if (id < 196608) {
        int id2 = id - 131072;
        int o = id2 >> 8, ci = id2 & 255;
        const float* s = w1 + (size_t)id2 * 9;
        const int chunk = ci >> 4, f = o >> 5;
        const int lane = (o & 31) + 32 * ((ci >> 3) & 1);
        const int j = ci & 7;
#pragma unroll
        for (int k = 0; k < 9; ++k)
            Wt1[((size_t)(chunk * 9 + k) * 8 + f) * 512 + lane * 8 + j] = (__bf16)s[k];
    } else {
        int id3 = id - 196608;     // 0..131071
        int sel = id3 >> 15;
        int k = id3 & 32767;
        const float* s = sel == 0 ? wq : sel == 1 ? wk : sel == 2 ? wv : wo;
        __bf16* d = sel == 0 ? wqb : sel == 1 ? wkb : sel == 2 ? wvb : wob;
        d[k] = (__bf16)s[k];
    }
}

// ---------------------------------------------------------------------------
// 1x1 projections via MFMA, outputs in MFMA-fragment-major order (unchanged).
// ---------------------------------------------------------------------------
__global__ __launch_bounds__(256) void proj_mfma_kernel(
    const __bf16* __restrict__ Xt0,   // [4][4096][512], in0 at cols 256-511
    const __bf16* __restrict__ Xin1,  // [4][4096][256]
    const __bf16* __restrict__ wqb, const __bf16* __restrict__ wkb,
    const __bf16* __restrict__ wvb,
    const float* __restrict__ bq, const float* __restrict__ bk,
    const float* __restrict__ bv,
    __bf16* __restrict__ Vswz, __bf16* __restrict__ Kswz, __bf16* __restrict__ Qswz)
{
    __shared__ __align__(16) __bf16 Vt[4][64][80];
    __shared__ float biasl[128];

    const int t = threadIdx.x;
    const int which = blockIdx.z % 3;
    const int b = blockIdx.z / 3;
    const int p0 = blockIdx.x * 128;

    const __bf16* W = which == 0 ? wqb : which == 1 ? wkb : wvb;
    const float* bias = which == 0 ? bq : which == 1 ? bk : bv;
    const __bf16* src; int stride, colb;
    if (which == 2) { src = Xin1 + (size_t)b * NN * 256; stride = 256; colb = 0; }
    else            { src = Xt0  + (size_t)b * NN * 512; stride = 512; colb = 256; }

    if (t < 128) biasl[t] = bias[t];
    __syncthreads();

    const int lane = t & 63, w = t >> 6;
    const int l31 = lane & 31, hi = lane >> 5;
    const int wo2 = w >> 1, wp2 = w & 1;
    const int ob = wo2 * 64;
    const int pb = p0 + wp2 * 64;

    f32x16 acc[2][2];
#pragma unroll
    for (int i = 0; i < 2; ++i)
#pragma unroll
        for (int j = 0; j < 2; ++j)
#pragma unroll
            for (int e = 0; e < 16; ++e) acc[i][j][e] = 0.f;

#pragma unroll
    for (int kc = 0; kc < 16; ++kc) {
        bf16x8 a0 = *(const bf16x8*)&W[(size_t)(ob + l31) * 256 + hi * 8 + kc * 16];
        bf16x8 a1 = *(const bf16x8*)&W[(size_t)(ob + 32 + l31) * 256 + hi * 8 + kc * 16];
        bf16x8 b0 = *(const bf16x8*)&src[(size_t)(pb + l31) * stride + colb + hi * 8 + kc * 16];
        bf16x8 b1 = *(const bf16x8*)&src[(size_t)(pb + 32 + l31) * stride + colb + hi * 8 + kc * 16];
        acc[0][0] = __builtin_amdgcn_mfma_f32_32x32x16_bf16(a0, b0, acc[0][0], 0, 0, 0);
        acc[0][1] = __builtin_amdgcn_mfma_f32_32x32x16_bf16(a0, b1, acc[0][1], 0, 0, 0);
        acc[1][0] = __builtin_amdgcn_mfma_f32_32x32x16_bf16(a1, b0, acc[1][0], 0, 0, 0);
        acc[1][1] = __builtin_amdgcn_mfma_f32_32x32x16_bf16(a1, b1, acc[1][1], 0, 0, 0);
    }

    if (which) {
        __bf16* dst = (which == 1 ? Kswz : Qswz) + (size_t)b * NN * CH_;
#pragma unroll
        for (int mi = 0; mi < 2; ++mi)
#pragma unroll
            for (int nx = 0; nx < 2; ++nx) {
                const int tile = (pb >> 5) + nx;
#pragma unroll
                for (int q4 = 0; q4 < 4; ++q4) {
                    const int ic = (ob >> 4) + mi * 2 + (q4 >> 1);
                    const int og = ob + mi * 32 + q4 * 8 + hi * 4;
                    __bf16 pk[4];
#pragma unroll
                    for (int j = 0; j < 4; ++j)
                        pk[j] = (__bf16)(acc[mi][nx][q4 * 4 + j] + biasl[og + j]);
                    const size_t el = ((size_t)(tile * 8 + ic) * 64
                                       + l31 + 32 * (q4 & 1)) * 8 + hi * 4;
                    *(uint2*)&dst[el] = *(const uint2*)pk;
                }
            }
    } else {
#pragma unroll
        for (int mi = 0; mi < 2; ++mi)
#pragma unroll
            for (int nx = 0; nx < 2; ++nx) {
                const int ploc = nx * 32 + l31;
#pragma unroll
                for (int q4 = 0; q4 < 4; ++q4) {
                    const int oloc = mi * 32 + q4 * 8 + hi * 4;
#pragma unroll
                    for (int j = 0; j < 4; ++j)
                        Vt[w][oloc + j][ploc] =
                            (__bf16)(acc[mi][nx][q4 * 4 + j] + biasl[ob + oloc + j]);
                }
            }
        __syncthreads();
        __bf16* dst = Vswz + (size_t)b * NN * CH_;
#pragma unroll
        for (int s = 0; s < 8; ++s) {
            const int tl = s >> 2, jc = (s >> 1) & 1, il = s & 1;
            const int tile_g = (pb >> 5) + tl;
            const int icf_g = (ob >> 5) + il;
            const int i_loc = il * 32 + l31;
            const int kk = tl * 32 + jc * 16 + hi * 8;
            uint4 v = *(const uint4*)&Vt[w][i_loc][kk];
            const size_t el = ((size_t)((tile_g * 2 + jc) * 4 + icf_g) * 64 + lane) * 8;
            *(uint4*)&dst[el] = v;
        }
    }
}

// ---------------------------------------------------------------------------
// MFMA bf16 flash attention (unchanged — verified, ~35us).
// ---------------------------------------------------------------------------
__global__ __launch_bounds__(256, 4) void attn_mfma_kernel(
    const __bf16* __restrict__ Qswz, const __bf16* __restrict__ Kswz,
    const __bf16* __restrict__ Vswz,
    __bf16* __restrict__ Opart, float* __restrict__ Mpart, float* __restrict__ Lpart)
{
    __shared__ __bf16 Op[4][128][34];
    __shared__ float Ml[4][32], Ll[4][32];

    const int t = threadIdx.x;
    const int lane = t & 63;
    const int w = t >> 6;
    const int l31 = lane & 31;
    const int hi = lane >> 5;

    const int bid = blockIdx.x;
    const int xcd = bid & 7;
    const int b = xcd >> 1;
    const int local = bid >> 3;
    const int qt = (xcd & 1) * 64 + (local & 63);
    const int half = local >> 6;
    const int q0 = qt * 32;

    const __bf16* Qs = Qswz + (size_t)b * NN * CH_ + (size_t)qt * 4096 + lane * 8;
    bf16x8 qf[8];
#pragma unroll
    for (int ic = 0; ic < 8; ++ic) qf[ic] = *(const bf16x8*)(Qs + ic * 512);

    const __bf16* Ks = Kswz + (size_t)b * NN * CH_ + lane * 8;
    const __bf16* Vs = Vswz + (size_t)b * NN * CH_ + lane * 8;

    f32x16 oacc[4];
#pragma unroll
    for (int i = 0; i < 4; ++i)
#pragma unroll
        for (int e = 0; e < 16; ++e) oacc[i][e] = 0.f;

    float m = -3e38f, lsum = 0.f;
    const int tbase = half * 64 + w * 16;

    for (int jt = 0; jt < 16; ++jt) {
        const int tile = tbase + jt;
        f32x16 s;
#pragma unroll
        for (int e = 0; e < 16; ++e) s[e] = 0.f;
        const __bf16* Kt = Ks + (size_t)tile * 4096;
#pragma unroll
        for (int ic = 0; ic < 8; ++ic) {
            bf16x8 kf = *(const bf16x8*)(Kt + ic * 512);
            s = __builtin_amdgcn_mfma_f32_32x32x16_bf16(kf, qf[ic], s, 0, 0, 0);
        }
        float t8[8];
#pragma unroll
        for (int e = 0; e < 8; ++e) t8[e] = fmaxf(s[e], s[e + 8]);
#pragma unroll
        for (int e = 0; e < 4; ++e) t8[e] = fmaxf(t8[e], t8[e + 4]);
        t8[0] = fmaxf(t8[0], t8[2]); t8[1] = fmaxf(t8[1], t8[3]);
        float mu = fmaxf(t8[0], t8[1]);
        const float pm = fmaxf(mu, __shfl_xor(mu, 32));
        if (!__all(pm <= m + 8.f)) {
            const float mn = fmaxf(m, pm);
            const float al = __expf(m - mn);
            m = mn;
            lsum *= al;
#pragma unroll
            for (int i = 0; i < 4; ++i)
#pragma unroll
                for (int e = 0; e < 16; ++e) oacc[i][e] *= al;
        }
#pragma unroll
        for (int e = 0; e < 16; ++e) s[e] = __expf(s[e] - m);
        float s8[8];
#pragma unroll
        for (int e = 0; e < 8; ++e) s8[e] = s[e] + s[e + 8];
#pragma unroll
        for (int e = 0; e < 4; ++e) s8[e] += s8[e + 4];
        s8[0] += s8[2]; s8[1] += s8[3];
        float su = s8[0] + s8[1];
        lsum += su + __shfl_xor(su, 32);

        const __bf16* Vt = Vs + (size_t)tile * 4096;
        {
            u32 w0 = pkbf(s[0], s[1]), w1 = pkbf(s[2], s[3]);
            u32 w2 = pkbf(s[4], s[5]), w3 = pkbf(s[6], s[7]);
            asm("v_permlane32_swap_b32 %0, %1" : "+v"(w0), "+v"(w2));
            asm("v_permlane32_swap_b32 %0, %1" : "+v"(w1), "+v"(w3));
            union { u32 u4[4]; bf16x8 v; } pB;
            pB.u4[0] = w0; pB.u4[1] = w1; pB.u4[2] = w2; pB.u4[3] = w3;
#pragma unroll
            for (int icf = 0; icf < 4; ++icf) {
                bf16x8 vf = *(const bf16x8*)(Vt + icf * 512);
                oacc[icf] = __builtin_amdgcn_mfma_f32_32x32x16_bf16(vf, pB.v, oacc[icf], 0, 0, 0);
            }
        }
        {
            u32 w0 = pkbf(s[8], s[9]), w1 = pkbf(s[10], s[11]);
            u32 w2 = pkbf(s[12], s[13]), w3 = pkbf(s[14], s[15]);
            asm("v_permlane32_swap_b32 %0, %1" : "+v"(w0), "+v"(w2));
            asm("v_permlane32_swap_b32 %0, %1" : "+v"(w1), "+v"(w3));
            union { u32 u4[4]; bf16x8 v; } pB;
            pB.u4[0] = w0; pB.u4[1] = w1; pB.u4[2] = w2; pB.u4[3] = w3;
#pragma unroll
            for (int icf = 0; icf < 4; ++icf) {
                bf16x8 vf = *(const bf16x8*)(Vt + 2048 + icf * 512);
                oacc[icf] = __builtin_amdgcn_mfma_f32_32x32x16_bf16(vf, pB.v, oacc[icf], 0, 0, 0);
            }
        }
    }

#pragma unroll
    for (int icf = 0; icf < 4; ++icf)
#pragma unroll
        for (int q = 0; q < 16; ++q) {
            const int row = icf * 32 + (q & 3) + 8 * (q >> 2) + 4 * hi;
            Op[w][row][l31] = (__bf16)oacc[icf][q];
        }
    if (hi == 0) { Ml[w][l31] = m; Ll[w][l31] = lsum; }
    __syncthreads();
    {
        const int q = t & 31;
        const int i0g = (t >> 5) * 16;
        const float m0 = Ml[0][q], m1 = Ml[1][q], m2 = Ml[2][q], m3 = Ml[3][q];
        const float ms = fmaxf(fmaxf(m0, m1), fmaxf(m2, m3));
        const float a0 = __expf(m0 - ms), a1 = __expf(m1 - ms);
        const float a2 = __expf(m2 - ms), a3 = __expf(m3 - ms);
        const float den = a0 * Ll[0][q] + a1 * Ll[1][q] + a2 * Ll[2][q] + a3 * Ll[3][q];
        union { __bf16 h[16]; uint4 u4[2]; } pk;
#pragma unroll
        for (int ii = 0; ii < 16; ++ii) {
            const int i = i0g + ii;
            pk.h[ii] = (__bf16)(a0 * (float)Op[0][i][q] + a1 * (float)Op[1][i][q]
                              + a2 * (float)Op[2][i][q] + a3 * (float)Op[3][i][q]);
        }
        const size_t base = ((size_t)((half * 4 + b) * NN) + q0 + q) * CH_ + i0g;
        *(uint4*)&Opart[base] = pk.u4[0];
        *(uint4*)&Opart[base + 8] = pk.u4[1];
        if (t < 32) {
            Mpart[(size_t)(half * 4 + b) * NN + q0 + q] = ms;
            Lpart[(size_t)(half * 4 + b) * NN + q0 + q] = den;
        }
    }
}

// ---------------------------------------------------------------------------
// Merge the 2 KV-half partials -> x0 bf16 pos-major [4][4096][128]
// ---------------------------------------------------------------------------
__global__ __launch_bounds__(256) void attn_merge_kernel(
    const __bf16* __restrict__ Opart, const float* __restrict__ Mpart,
    const float* __restrict__ Lpart, __bf16* __restrict__ x0)
{
    const int id = blockIdx.x * 256 + threadIdx.x;
    const int qg = id >> 2;
    const int i0 = (id & 3) * 32;
    const int b = qg >> 12, q = qg & 4095;
    const size_t idx0 = (size_t)b * NN + q;
    const size_t idx1 = (size_t)(4 + b) * NN + q;
    const float m0 = Mpart[idx0], m1 = Mpart[idx1];
    const float ms = fmaxf(m0, m1);
    const float a0 = __expf(m0 - ms), a1 = __expf(m1 - ms);
    const float inv = 1.f / (a0 * Lpart[idx0] + a1 * Lpart[idx1]);
    const __bf16* O0 = &Opart[idx0 * CH_ + i0];
    const __bf16* O1 = &Opart[idx1 * CH_ + i0];
    union { __bf16 h[32]; uint4 u4[4]; } ov;
#pragma unroll
    for (int ii = 0; ii < 32; ++ii)
        ov.h[ii] = (__bf16)((a0 * (float)O0[ii] + a1 * (float)O1[ii]) * inv);
    uint4* dst = (uint4*)&x0[((size_t)b * NN + q) * CH_ + i0];
#pragma unroll
    for (int s = 0; s < 4; ++s) dst[s] = ov.u4[s];
}

// ---------------------------------------------------------------------------
// conv_o (1x1, 128->256) via MFMA + BN + GELU -> Xt0 cols 0-255 (unchanged)
// ---------------------------------------------------------------------------
__global__ __launch_bounds__(256) void convo_mfma_kernel(
    const __bf16* __restrict__ x0, const __bf16* __restrict__ wob,
    const float* __restrict__ bo,
    const float* __restrict__ g, const float* __restrict__ bb,
    const float* __restrict__ mm, const float* __restrict__ vv,
    __bf16* __restrict__ Xt0)
{
    __shared__ float scb[128], shb[128], bsb[128];
    const int t = threadIdx.x;
    const int p0 = blockIdx.x * 128;
    const int o0 = blockIdx.y * 128;
    const int b = blockIdx.z;
    if (t < 128) {
        const int o = o0 + t;
        const float sc = g[o] * rsqrtf(vv[o] + 1e-5f);
        scb[t] = sc; shb[t] = bb[o] - mm[o] * sc; bsb[t] = bo[o];
    }
    __syncthreads();

    const int lane = t & 63, w = t >> 6;
    const int l31 = lane & 31, hi = lane >> 5;
    const int wo2 = w >> 1, wp2 = w & 1;
    const int ob = o0 + wo2 * 64;
    const int pb = p0 + wp2 * 64;

    f32x16 acc[2][2];
#pragma unroll
    for (int i = 0; i < 2; ++i)
#pragma unroll
        for (int j = 0; j < 2; ++j)
#pragma unroll
            for (int e = 0; e < 16; ++e) acc[i][j][e] = 0.f;

#pragma unroll
    for (int kc = 0; kc < 8; ++kc) {
        bf16x8 a0 = *(const bf16x8*)&wob[(size_t)(ob + l31) * 128 + hi * 8 + kc * 16];
        bf16x8 a1 = *(const bf16x8*)&wob[(size_t)(ob + 32 + l31) * 128 + hi * 8 + kc * 16];
        bf16x8 b0 = *(const bf16x8*)&x0[((size_t)(b * NN) + pb + l31) * 128 + hi * 8 + kc * 16];
        bf16x8 b1 = *(const bf16x8*)&x0[((size_t)(b * NN) + pb + 32 + l31) * 128 + hi * 8 + kc * 16];
        acc[0][0] = __builtin_amdgcn_mfma_f32_32x32x16_bf16(a0, b0, acc[0][0], 0, 0, 0);
        acc[0][1] = __builtin_amdgcn_mfma_f32_32x32x16_bf16(a0, b1, acc[0][1], 0, 0, 0);
        acc[1][0] = __builtin_amdgcn_mfma_f32_32x32x16_bf16(a1, b0, acc[1][0], 0, 0, 0);
        acc[1][1] = __builtin_amdgcn_mfma_f32_32x32x16_bf16(a1, b1, acc[1][1], 0, 0, 0);
    }

#pragma unroll
    for (int mi = 0; mi < 2; ++mi)
#pragma unroll
        for (int nx = 0; nx < 2; ++nx) {
            const int p = pb + nx * 32 + l31;
            const size_t rowbase = ((size_t)(b * NN) + p) * 512 + o0;
#pragma unroll
            for (int q4 = 0; q4 < 4; ++q4) {
                const int ol = wo2 * 64 + mi * 32 + q4 * 8 + hi * 4;
                __bf16 pk[4];
#pragma unroll
                for (int j = 0; j < 4; ++j) {
                    float v = acc[mi][nx][q4 * 4 + j] + bsb[ol + j];
                    v = v * scb[ol + j] + shb[ol + j];
                    pk[j] = (__bf16)gelu_erf(v);
                }
                *(uint2*)&Xt0[rowbase + ol] = *(const uint2*)pk;
            }
        }
}

// ---------------------------------------------------------------------------
// 3x3 conv via MFMA. Weights held in REGISTERS per ci-chunk (wA[9][2], 72
// VGPR), loaded as 18 back-to-back coalesced frag-major loads — R9's 52-VGPR
// allocation serialized these into ~9 L2 round-trips per chunk.
// Block: 2 waves (128 thr) = 64 o x 64 pos (1 output row); grid 1024
// -> 4 blocks/CU. LDS: 3-row input tile double-buffered (2 x 6336 B).
// ---------------------------------------------------------------------------
template<int IC>
__global__ __launch_bounds__(128) void conv3x3_mfma_kernel(
    const __bf16* __restrict__ Xsrc,   // NHWC [4][4096][IC]
    const __bf16* __restrict__ Wf,     // frag-major [NC][9][8][64][8]
    const float* __restrict__ bias, const float* __restrict__ bng,
    const float* __restrict__ bnb, const float* __restrict__ bnm,
    const float* __restrict__ bnv,
    __bf16* __restrict__ out)          // NHWC [4][4096][256]
{
    constexpr int NC = IC / 16;
    __shared__ __align__(16) char Tl[2][6336];   // [3 rows][66 xh][16 ci] bf16
    __shared__ float scb[64], shb[64], bsb[64];

    const int t = threadIdx.x;
    const int bid = blockIdx.x;
    const int xcd = bid & 7, local = bid >> 3;        // 1024 blocks
    const int combo = xcd * 2 + (local >> 6);         // 0..15, pinned per XCD
    const int y0 = local & 63;                        // output row
    const int m = combo & 3, b = combo >> 2;
    const int o0 = m * 64;

    if (t < 64) {
        const int o = o0 + t;
        const float sc = bng[o] * rsqrtf(bnv[o] + 1e-5f);
        scb[t] = sc; shb[t] = bnb[o] - bnm[o] * sc; bsb[t] = bias[o];
    }

    const int lane = t & 63, w = t >> 6;   // w = x-half (0,1)
    const int l31 = lane & 31, hi = lane >> 5;

    uint4 ireg[3];

    auto loadI = [&](int c0) {
#pragma unroll
        for (int s = 0; s < 3; ++s) {
            int u = t + s * 128;
            int g = u & 1, x = (u >> 1) & 63, r = u >> 7;   // r 0..2
            int yy = y0 - 1 + r;
            if (yy >= 0 && yy < 64)
                ireg[s] = *(const uint4*)&Xsrc[((size_t)(b * 4096 + yy * 64 + x)) * IC + c0 + g * 8];
            else
                ireg[s] = make_uint4(0u, 0u, 0u, 0u);
        }
    };
    auto writeI = [&](char* dst) {
#pragma unroll
        for (int s = 0; s < 3; ++s) {
            int u = t + s * 128;
            int g = u & 1, x = (u >> 1) & 63, r = u >> 7;
            int xh = x + 1;
            int byte = r * 2112 + ((xh * 32 + g * 16) ^ ((xh & 7) << 4));
            *(uint4*)(dst + byte) = ireg[s];
        }
        if (t < 12) {   // x halo zeros (xh=0 and 65) for 3 rows x 2 ci-halves
            int g = t & 1, side = (t >> 1) & 1, r = t >> 2;   // r 0..2
            int xh = side ? 65 : 0;
            int byte = r * 2112 + ((xh * 32 + g * 16) ^ ((xh & 7) << 4));
            *(uint4*)(dst + byte) = make_uint4(0u, 0u, 0u, 0u);
        }
    };

    // weights in registers, 18 frag loads per chunk, statically indexed
    const __bf16* Wb = Wf + ((size_t)(m * 2) * 64 + lane) * 8;
    bf16x8 wA[9][2];
    auto loadA = [&](int c) {
#pragma unroll
        for (int k9 = 0; k9 < 9; ++k9) {
            const __bf16* wp = Wb + (size_t)(c * 9 + k9) * 4096;
            wA[k9][0] = *(const bf16x8*)(wp);
            wA[k9][1] = *(const bf16x8*)(wp + 512);
        }
    };

    f32x16 acc[2];
#pragma unroll
    for (int i = 0; i < 2; ++i)
#pragma unroll
        for (int e = 0; e < 16; ++e) acc[i][e] = 0.f;

    int Boff[3];
#pragma unroll
    for (int dx = 0; dx < 3; ++dx) {
        int xh = w * 32 + l31 + dx;
        Boff[dx] = (xh * 32 + hi * 16) ^ ((xh & 7) << 4);
    }

    auto compute = [&](const char* Tb) {
#pragma unroll
        for (int k9 = 0; k9 < 9; ++k9) {
            const int dy = k9 / 3, dx = k9 % 3;
            bf16x8 bv = *(const bf16x8*)(Tb + dy * 2112 + Boff[dx]);
            acc[0] = __builtin_amdgcn_mfma_f32_32x32x16_bf16(wA[k9][0], bv, acc[0], 0, 0, 0);
            acc[1] = __builtin_amdgcn_mfma_f32_32x32x16_bf16(wA[k9][1], bv, acc[1], 0, 0, 0);
        }
    };

    loadI(0); loadA(0);
    writeI(Tl[0]);
    __syncthreads();
    for (int c = 0; c < NC; ++c) {
        const int cur = c & 1;
        if (c + 1 < NC) loadI((c + 1) * 16);
        compute(Tl[cur]);
        if (c + 1 < NC) loadA(c + 1);   // wA dead after compute; hide L2 latency
        __syncthreads();
        if (c + 1 < NC) writeI(Tl[cur ^ 1]);
        __syncthreads();
    }

    // epilogue: bias + BN + GELU, store NHWC bf16
    {
        const int p = y0 * 64 + w * 32 + l31;
        const size_t rowbase = ((size_t)(b * 4096 + p)) * 256 + o0;
#pragma unroll
        for (int mi = 0; mi < 2; ++mi)
#pragma unroll
            for (int q = 0; q < 4; ++q) {
                const int obase = mi * 32 + q * 8 + hi * 4;
                __bf16 pk[4];
#pragma unroll
                for (int j = 0; j < 4; ++j) {
                    float v = acc[mi][q * 4 + j] + bsb[obase + j];
                    v = v * scb[obase + j] + shb[obase + j];
                    pk[j] = (__bf16)gelu_erf(v);
                }
                *(uint2*)&out[rowbase + obase] = *(const uint2*)pk;
            }
    }
}

// ---------------------------------------------------------------------------
// global max of (y1 + x0gelu) over spatial, two stages
// ---------------------------------------------------------------------------
__global__ __launch_bounds__(256) void maxpart_kernel(
    const __bf16* __restrict__ y1, const __bf16* __restrict__ xt0,
    float* __restrict__ part)
{
    const int o = threadIdx.x;
    const int chunk = blockIdx.x & 63;
    const int b = blockIdx.x >> 6;
    float mx = -1e30f;
    for (int pp = 0; pp < 64; ++pp) {
        int p = chunk * 64 + pp;
        float a = (float)y1[((size_t)(b * 4096 + p)) * 256 + o];
        float c = (float)xt0[((size_t)(b * 4096 + p)) * 512 + o];
        mx = fmaxf(mx, a + c);
    }
    part[((size_t)(b * 64 + chunk)) * 256 + o] = mx;
}

__global__ __launch_bounds__(256) void maxfin_kernel(
    const float* __restrict__ part, float* __restrict__ out)
{
    const int o = threadIdx.x;
    const int b = blockIdx.x;
    float mx = -1e30f;
    for (int c = 0; c < 64; ++c)
        mx = fmaxf(mx, part[((size_t)(b * 64 + c)) * 256 + o]);
    out[b * 256 + o] = mx;
}

// ---------------------------------------------------------------------------
extern "C" void kernel_launch(void* const* d_in, const int* in_sizes, int n_in,
                              void* d_out, int out_size, void* d_ws, size_t ws_size,
                              hipStream_t stream)
{
    const float* in0  = (const float*)d_in[0];
    const float* in1  = (const float*)d_in[1];
    const float* w_q  = (const float*)d_in[2];
    const float* b_q  = (const float*)d_in[3];
    const float* w_k  = (const float*)d_in[4];
    const float* b_k  = (const float*)d_in[5];
    const float* w_v  = (const float*)d_in[6];
    const float* b_v  = (const float*)d_in[7];
    const float* w_o  = (const float*)d_in[8];
    const float* b_o  = (const float*)d_in[9];
    const float* bn0g = (const float*)d_in[10];
    const float* bn0b = (const float*)d_in[11];
    const float* bn0m = (const float*)d_in[12];
    const float* bn0v = (const float*)d_in[13];
    const float* cbw0 = (const float*)d_in[14];
    const float* cbb0 = (const float*)d_in[15];
    const float* cb0g = (const float*)d_in[16];
    const float* cb0b = (const float*)d_in[17];
    const float* cb0m = (const float*)d_in[18];
    const float* cb0v = (const float*)d_in[19];
    const float* cbw1 = (const float*)d_in[20];
    const float* cbb1 = (const float*)d_in[21];
    const float* cb1g = (const float*)d_in[22];
    const float* cb1b = (const float*)d_in[23];
    const float* cb1m = (const float*)d_in[24];
    const float* cb1v = (const float*)d_in[25];

    char* wsb = (char*)d_ws;
    const size_t MB = 1u << 20;
    __bf16* Xt0  = (__bf16*)(wsb);
    __bf16* Xin1 = (__bf16*)(wsb + 16 * MB);
    __bf16* Opart= (__bf16*)(wsb + 16 * MB);
    __bf16* Qswz = (__bf16*)(wsb + 24 * MB);
    __bf16* x0   = (__bf16*)(wsb + 24 * MB);
    __bf16* Kswz = (__bf16*)(wsb + 28 * MB);
    __bf16* y0   = (__bf16*)(wsb + 24 * MB);
    __bf16* Vswz = (__bf16*)(wsb + 32 * MB);
    __bf16* y1   = (__bf16*)(wsb + 32 * MB);
    __bf16* wqb  = (__bf16*)(wsb + 40 * MB);
    __bf16* wkb  = (__bf16*)(wsb + 40 * MB + 65536);
    __bf16* wvb  = (__bf16*)(wsb + 40 * MB + 2 * 65536);
    __bf16* wob  = (__bf16*)(wsb + 40 * MB + 3 * 65536);
    __bf16* Wt0  = (__bf16*)(wsb + 40 * MB + 4 * 65536);              // 2359296 B
    __bf16* Wt1  = (__bf16*)(wsb + 40 * MB + 4 * 65536 + 2359296);    // 1179648 B
    float*  Mpart= (float*)(wsb + 44 * MB);
    float*  Lpart= (float*)(wsb + 44 * MB + 131072);
    float*  part = (float*)(wsb + 44 * MB + 2 * 131072);
    float* outp = (float*)d_out;

    nhwc_cast_kernel<<<dim3(64, 4, 4), 256, 0, stream>>>(in0, Xt0, 256, 512);
    nhwc_cast_kernel<<<dim3(64, 4, 4), 256, 0, stream>>>(in1, Xin1, 0, 256);
    wtrans_kernel<<<1280, 256, 0, stream>>>(cbw0, cbw1, w_q, w_k, w_v, w_o,
                                            Wt0, Wt1, wqb, wkb, wvb, wob);
    proj_mfma_kernel<<<dim3(32, 1, 12), 256, 0, stream>>>(
        Xt0, Xin1, wqb, wkb, wvb, b_q, b_k, b_v, Vswz, Kswz, Qswz);
    attn_mfma_kernel<<<1024, 256, 0, stream>>>(Qswz, Kswz, Vswz, Opart, Mpart, Lpart);
    attn_merge_kernel<<<256, 256, 0, stream>>>(Opart, Mpart, Lpart, x0);
    convo_mfma_kernel<<<dim3(32, 2, 4), 256, 0, stream>>>(
        x0, wob, b_o, bn0g, bn0b, bn0m, bn0v, Xt0);
    conv3x3_mfma_kernel<512><<<1024, 128, 0, stream>>>(Xt0, Wt0, cbb0, cb0g, cb0b, cb0m, cb0v, y0);
    conv3x3_mfma_kernel<256><<<1024, 128, 0, stream>>>(y0, Wt1, cbb1, cb1g, cb1b, cb1m, cb1v, y1);
    maxpart_kernel<<<256, 256, 0, stream>>>(y1, Xt0, part);
    maxfin_kernel<<<4, 256, 0, stream>>>(part, outp);
}